// Round 1
// baseline (969.442 us; speedup 1.0000x reference)
//
#include <hip/hip_runtime.h>
#include <hip/hip_bf16.h>
#include <math.h>

#define NNODES 50000
#define NEDGES 640000
#define DIM    128
#define PEDIM  37
#define KTOT   165   // DIM + PEDIM
#define NLAYERS 3

static constexpr size_t alignup(size_t x) { return (x + 255) & ~size_t(255); }
static constexpr size_t OFF_X    = 0;
static constexpr size_t OFF_H    = alignup(OFF_X   + (size_t)NNODES * DIM * 4);
static constexpr size_t OFF_O    = alignup(OFF_H   + (size_t)NNODES * DIM * 4);
static constexpr size_t OFF_HL   = alignup(OFF_O   + (size_t)NNODES * DIM * 4);
static constexpr size_t OFF_HR   = alignup(OFF_HL  + (size_t)NNODES * 4);
static constexpr size_t OFF_OFFS = alignup(OFF_HR  + (size_t)NNODES * 4);
static constexpr size_t OFF_CUR  = alignup(OFF_OFFS + (size_t)(NNODES + 1) * 4);
static constexpr size_t OFF_CSR  = alignup(OFF_CUR + (size_t)NNODES * 4);
static constexpr size_t OFF_B    = alignup(OFF_CSR + (size_t)NEDGES * 4);
static constexpr size_t OFF_B2   = alignup(OFF_B   + (size_t)KTOT * DIM * 4);
static constexpr size_t OFF_ET   = alignup(OFF_B2  + (size_t)DIM * 4);
static constexpr size_t OFF_GS   = alignup(OFF_ET  + 16 * 4);
static constexpr size_t OFF_GS2  = alignup(OFF_GS  + (size_t)DIM * 4);
static constexpr size_t WS_NEED  = alignup(OFF_GS2 + (size_t)DIM * 4);

// ---------------- CSR build ----------------

__global__ void k_zero_int(int* __restrict__ p, int n) {
    for (int i = blockIdx.x * blockDim.x + threadIdx.x; i < n; i += gridDim.x * blockDim.x)
        p[i] = 0;
}

__global__ void k_count(const int* __restrict__ dstv, int* __restrict__ cnt) {
    for (int e = blockIdx.x * blockDim.x + threadIdx.x; e < NEDGES; e += gridDim.x * blockDim.x)
        atomicAdd(&cnt[dstv[e]], 1);
}

// cnt_cur: counts in, exclusive-prefix out (becomes fill cursor). offs[N+1] written.
__global__ __launch_bounds__(1024) void k_scan(int* __restrict__ cnt_cur, int* __restrict__ offs) {
    __shared__ int sums[1024];
    const int t = threadIdx.x;
    const int CH = (NNODES + 1023) / 1024;  // 49
    const int lo = t * CH;
    const int hi = (lo + CH < NNODES) ? lo + CH : NNODES;
    int s = 0;
    for (int i = lo; i < hi; ++i) s += cnt_cur[i];
    sums[t] = s;
    __syncthreads();
    for (int d = 1; d < 1024; d <<= 1) {
        int v = (t >= d) ? sums[t - d] : 0;
        __syncthreads();
        sums[t] += v;
        __syncthreads();
    }
    int run = (t == 0) ? 0 : sums[t - 1];
    for (int i = lo; i < hi; ++i) {
        int c = cnt_cur[i];
        offs[i] = run;
        cnt_cur[i] = run;
        run += c;
    }
    if (t == 1023) offs[NNODES] = sums[1023];
}

__global__ void k_fill(const int* __restrict__ srcv, const int* __restrict__ dstv,
                       const int* __restrict__ attr, int* __restrict__ cur,
                       int* __restrict__ csr) {
    for (int e = blockIdx.x * blockDim.x + threadIdx.x; e < NEDGES; e += gridDim.x * blockDim.x) {
        int d = dstv[e];
        int pos = atomicAdd(&cur[d], 1);
        csr[pos] = (srcv[e] & 0xFFFF) | (attr[e] << 16);
    }
}

// ---------------- per-layer parameter prep ----------------
// Bmat[165][128]: rows 0..127 = linW, rows 128..164 = peW @ linW.
// b2 = pe_b @ linW. et[t] = dot(edge_emb[t], attn_e). Zero BN accumulators.
__global__ __launch_bounds__(512) void k_params(
    const float* __restrict__ linW, const float* __restrict__ peW,
    const float* __restrict__ peb, const float* __restrict__ attn_e,
    const float* __restrict__ edge_emb,
    float* __restrict__ Bmat, float* __restrict__ b2, float* __restrict__ et,
    float* __restrict__ gsum, float* __restrict__ gsumsq) {
    const int tid = threadIdx.x;
    const int j = tid & 127;
    const int q = tid >> 7;  // 0..3
    for (int k = q; k < DIM; k += 4)
        Bmat[k * DIM + j] = linW[k * DIM + j];
    for (int p = q; p < PEDIM; p += 4) {
        float s = 0.f;
        #pragma unroll 8
        for (int d = 0; d < DIM; ++d) s += peW[p * DIM + d] * linW[d * DIM + j];
        Bmat[(DIM + p) * DIM + j] = s;
    }
    if (q == 0) {
        float s = 0.f;
        #pragma unroll 8
        for (int d = 0; d < DIM; ++d) s += peb[d] * linW[d * DIM + j];
        b2[j] = s;
    }
    if (tid < 9) {
        float s = 0.f;
        #pragma unroll 8
        for (int d = 0; d < DIM; ++d) s += edge_emb[tid * DIM + d] * attn_e[d];
        et[tid] = s;
    }
    if (tid < DIM) { gsum[tid] = 0.f; gsumsq[tid] = 0.f; }
}

// ---------------- fused GEMM: h = [x|PE] @ Bmat + b2, plus hl/hr ----------------
__global__ __launch_bounds__(256) void k_gemm(
    const float* __restrict__ X, const float* __restrict__ PE,
    const float* __restrict__ Bmat, const float* __restrict__ b2,
    const float* __restrict__ attn_l, const float* __restrict__ attn_r,
    float* __restrict__ H, float* __restrict__ HL, float* __restrict__ HR) {
    __shared__ float Als[64 * 166];      // padded stride 166 (conflict-free)
    __shared__ float Bls[KTOT * DIM];
    const int tid = threadIdx.x;
    const int row0 = blockIdx.x * 64;

    {   // stage B: 21120 floats = 5280 float4
        const float4* s = (const float4*)Bmat;
        float4* d = (float4*)Bls;
        for (int i = tid; i < (KTOT * DIM) / 4; i += 256) d[i] = s[i];
    }
    {   // stage A (x | PE), zero-pad OOB rows
        const int wv = tid >> 6, lane = tid & 63;
        for (int r = wv; r < 64; r += 4) {
            const int gr = row0 + r;
            const bool ok = gr < NNODES;
            for (int k = lane; k < KTOT; k += 64) {
                float v = 0.f;
                if (ok) v = (k < DIM) ? X[(size_t)gr * DIM + k] : PE[(size_t)gr * PEDIM + (k - DIM)];
                Als[r * 166 + k] = v;
            }
        }
    }
    __syncthreads();

    const int cg = tid & 15, rg = tid >> 4;   // 16x16 thread tile: 4 rows x 8 cols each
    float acc[4][8];
    #pragma unroll
    for (int i = 0; i < 4; ++i)
        #pragma unroll
        for (int j = 0; j < 8; ++j) acc[i][j] = 0.f;

    #pragma unroll 3
    for (int k = 0; k < KTOT; ++k) {
        const float a0 = Als[(rg * 4 + 0) * 166 + k];
        const float a1 = Als[(rg * 4 + 1) * 166 + k];
        const float a2 = Als[(rg * 4 + 2) * 166 + k];
        const float a3 = Als[(rg * 4 + 3) * 166 + k];
        const float4 bq0 = *(const float4*)&Bls[k * DIM + cg * 8];
        const float4 bq1 = *(const float4*)&Bls[k * DIM + cg * 8 + 4];
        const float b[8] = {bq0.x, bq0.y, bq0.z, bq0.w, bq1.x, bq1.y, bq1.z, bq1.w};
        #pragma unroll
        for (int j = 0; j < 8; ++j) {
            acc[0][j] = fmaf(a0, b[j], acc[0][j]);
            acc[1][j] = fmaf(a1, b[j], acc[1][j]);
            acc[2][j] = fmaf(a2, b[j], acc[2][j]);
            acc[3][j] = fmaf(a3, b[j], acc[3][j]);
        }
    }

    float b2v[8], alv[8], arv[8];
    #pragma unroll
    for (int j = 0; j < 8; ++j) {
        b2v[j] = b2[cg * 8 + j];
        alv[j] = attn_l[cg * 8 + j];
        arv[j] = attn_r[cg * 8 + j];
    }
    #pragma unroll
    for (int i = 0; i < 4; ++i)
        #pragma unroll
        for (int j = 0; j < 8; ++j) acc[i][j] += b2v[j];

    #pragma unroll
    for (int i = 0; i < 4; ++i) {
        const int row = row0 + rg * 4 + i;
        float sl = 0.f, sr = 0.f;
        #pragma unroll
        for (int j = 0; j < 8; ++j) { sl = fmaf(acc[i][j], alv[j], sl); sr = fmaf(acc[i][j], arv[j], sr); }
        #pragma unroll
        for (int m = 1; m < 16; m <<= 1) {
            sl += __shfl_xor(sl, m, 16);
            sr += __shfl_xor(sr, m, 16);
        }
        if (row < NNODES) {
            if (cg == 0) { HL[row] = sl; HR[row] = sr; }
            *(float4*)&H[(size_t)row * DIM + cg * 8] = make_float4(acc[i][0], acc[i][1], acc[i][2], acc[i][3]);
            *(float4*)&H[(size_t)row * DIM + cg * 8 + 4] = make_float4(acc[i][4], acc[i][5], acc[i][6], acc[i][7]);
        }
    }
}

// ---------------- per-node softmax + aggregation (one wave per node) ----------------
__global__ __launch_bounds__(256) void k_agg(
    const int* __restrict__ offs, const int* __restrict__ csr,
    const float* __restrict__ HL, const float* __restrict__ HR,
    const float* __restrict__ et, const float* __restrict__ H,
    const float* __restrict__ bias, float* __restrict__ OUT) {
    const int lane = threadIdx.x & 63;
    const int node = blockIdx.x * 4 + (threadIdx.x >> 6);
    if (node >= NNODES) return;
    const int off0 = offs[node];
    const int deg = offs[node + 1] - off0;

    const float hri = HR[node];
    float myAlpha = 0.f;
    int myEntry = 0;
    float mx = -1e30f;
    for (int j = lane; j < deg; j += 64) {
        const int en = csr[off0 + j];
        float al = HL[en & 0xFFFF] + hri + et[en >> 16];
        al = al > 0.f ? al : 0.2f * al;
        if (j < 64) { myAlpha = al; myEntry = en; }
        mx = fmaxf(mx, al);
    }
    #pragma unroll
    for (int m = 1; m < 64; m <<= 1) mx = fmaxf(mx, __shfl_xor(mx, m, 64));

    float s = 0.f;
    if (deg <= 64) {
        if (lane < deg) s = __expf(myAlpha - mx);
    } else {
        for (int j = lane; j < deg; j += 64) {
            const int en = csr[off0 + j];
            float al = HL[en & 0xFFFF] + hri + et[en >> 16];
            al = al > 0.f ? al : 0.2f * al;
            s += __expf(al - mx);
        }
    }
    #pragma unroll
    for (int m = 1; m < 64; m <<= 1) s += __shfl_xor(s, m, 64);
    const float invd = (deg > 0) ? 1.f / s : 0.f;

    float2 acc = make_float2(0.f, 0.f);
    if (deg <= 64) {
        for (int j = 0; j < deg; ++j) {
            const float al = __shfl(myAlpha, j, 64);
            const int en = __shfl(myEntry, j, 64);
            const float w = __expf(al - mx) * invd;
            const float2 hv = *(const float2*)&H[(size_t)(en & 0xFFFF) * DIM + lane * 2];
            acc.x = fmaf(w, hv.x, acc.x);
            acc.y = fmaf(w, hv.y, acc.y);
        }
    } else {
        for (int j = 0; j < deg; ++j) {
            const int en = csr[off0 + j];
            float al = HL[en & 0xFFFF] + hri + et[en >> 16];
            al = al > 0.f ? al : 0.2f * al;
            const float w = __expf(al - mx) * invd;
            const float2 hv = *(const float2*)&H[(size_t)(en & 0xFFFF) * DIM + lane * 2];
            acc.x = fmaf(w, hv.x, acc.x);
            acc.y = fmaf(w, hv.y, acc.y);
        }
    }
    float2 o = make_float2(acc.x + bias[lane * 2], acc.y + bias[lane * 2 + 1]);
    *(float2*)&OUT[(size_t)node * DIM + lane * 2] = o;
}

// ---------------- BN stats (column sum / sumsq) ----------------
__global__ __launch_bounds__(256) void k_bnstats(
    const float* __restrict__ OUT, float* __restrict__ gsum, float* __restrict__ gsumsq) {
    __shared__ float ls[256], ls2[256];
    const int c = threadIdx.x & 127;
    const int half = threadIdx.x >> 7;
    const int rend = min(NNODES, (int)(blockIdx.x * 256 + 256));
    float s = 0.f, s2 = 0.f;
    for (int r = blockIdx.x * 256 + half; r < rend; r += 2) {
        const float v = OUT[(size_t)r * DIM + c];
        s += v;
        s2 = fmaf(v, v, s2);
    }
    ls[threadIdx.x] = s;
    ls2[threadIdx.x] = s2;
    __syncthreads();
    if (half == 0) {
        atomicAdd(&gsum[c], ls[c] + ls[c + 128]);
        atomicAdd(&gsumsq[c], ls2[c] + ls2[c + 128]);
    }
}

// ---------------- apply: BN (train-mode batch stats) + residual ----------------
__global__ __launch_bounds__(256) void k_apply_bn(
    const float* __restrict__ OUT, const float* __restrict__ XPREV,
    const float* __restrict__ gsum, const float* __restrict__ gsumsq,
    const float* __restrict__ gamma, const float* __restrict__ beta,
    float* __restrict__ XNEXT) {
    const int idx = blockIdx.x * 256 + threadIdx.x;
    const int c = idx & 127;
    const float mu = gsum[c] * (1.f / NNODES);
    const float var = gsumsq[c] * (1.f / NNODES) - mu * mu;
    const float sc = gamma[c] * rsqrtf(var + 1e-5f);
    XNEXT[idx] = (OUT[idx] - mu) * sc + beta[c] + XPREV[idx];
}

__global__ __launch_bounds__(256) void k_apply_last(
    const float* __restrict__ OUT, const float* __restrict__ XPREV, float* __restrict__ XF) {
    const int idx = blockIdx.x * 256 + threadIdx.x;
    XF[idx] = OUT[idx] + XPREV[idx];
}

// ---------------- host ----------------
extern "C" void kernel_launch(void* const* d_in, const int* in_sizes, int n_in,
                              void* d_out, int out_size, void* d_ws, size_t ws_size,
                              hipStream_t stream) {
    const float* X_n      = (const float*)d_in[0];
    const float* PE       = (const float*)d_in[1];
    const int*   eidx     = (const int*)d_in[2];
    const int*   eattr    = (const int*)d_in[3];
    const float* edge_emb = (const float*)d_in[4];
    const float* pe_W     = (const float*)d_in[5];
    const float* pe_b     = (const float*)d_in[6];
    const float* lin_W    = (const float*)d_in[7];
    const float* attn_l   = (const float*)d_in[8];
    const float* attn_r   = (const float*)d_in[9];
    const float* attn_e   = (const float*)d_in[10];
    const float* bias     = (const float*)d_in[11];
    const float* bng      = (const float*)d_in[12];
    const float* bnb      = (const float*)d_in[13];

    if (ws_size < WS_NEED) return;  // scratch too small: fail loudly (wrong output)

    char* ws = (char*)d_ws;
    float* xbuf   = (float*)(ws + OFF_X);
    float* hbuf   = (float*)(ws + OFF_H);
    float* obuf   = (float*)(ws + OFF_O);
    float* hl     = (float*)(ws + OFF_HL);
    float* hr     = (float*)(ws + OFF_HR);
    int*   offs   = (int*)(ws + OFF_OFFS);
    int*   cur    = (int*)(ws + OFF_CUR);
    int*   csr    = (int*)(ws + OFF_CSR);
    float* Bmat   = (float*)(ws + OFF_B);
    float* b2     = (float*)(ws + OFF_B2);
    float* et     = (float*)(ws + OFF_ET);
    float* gsum   = (float*)(ws + OFF_GS);
    float* gsumsq = (float*)(ws + OFF_GS2);

    const int* srcv = eidx;
    const int* dstv = eidx + NEDGES;

    // CSR build (dst is layer-invariant)
    hipLaunchKernelGGL(k_zero_int, dim3(256), dim3(256), 0, stream, cur, NNODES);
    hipLaunchKernelGGL(k_count, dim3(1024), dim3(256), 0, stream, dstv, cur);
    hipLaunchKernelGGL(k_scan, dim3(1), dim3(1024), 0, stream, cur, offs);
    hipLaunchKernelGGL(k_fill, dim3(1024), dim3(256), 0, stream, srcv, dstv, eattr, cur, csr);

    const float* xin = X_n;
    for (int l = 0; l < NLAYERS; ++l) {
        hipLaunchKernelGGL(k_params, dim3(1), dim3(512), 0, stream,
                           lin_W + (size_t)l * DIM * DIM, pe_W + (size_t)l * PEDIM * DIM,
                           pe_b + (size_t)l * DIM, attn_e + (size_t)l * DIM,
                           edge_emb + (size_t)l * 9 * DIM,
                           Bmat, b2, et, gsum, gsumsq);
        hipLaunchKernelGGL(k_gemm, dim3((NNODES + 63) / 64), dim3(256), 0, stream,
                           xin, PE, Bmat, b2, attn_l + (size_t)l * DIM, attn_r + (size_t)l * DIM,
                           hbuf, hl, hr);
        hipLaunchKernelGGL(k_agg, dim3((NNODES + 3) / 4), dim3(256), 0, stream,
                           offs, csr, hl, hr, et, hbuf, bias + (size_t)l * DIM, obuf);
        if (l < NLAYERS - 1) {
            hipLaunchKernelGGL(k_bnstats, dim3((NNODES + 255) / 256), dim3(256), 0, stream,
                               obuf, gsum, gsumsq);
            hipLaunchKernelGGL(k_apply_bn, dim3(NNODES * DIM / 256), dim3(256), 0, stream,
                               obuf, xin, gsum, gsumsq, bng + (size_t)l * DIM, bnb + (size_t)l * DIM,
                               xbuf);
            xin = xbuf;
        } else {
            hipLaunchKernelGGL(k_apply_last, dim3(NNODES * DIM / 256), dim3(256), 0, stream,
                               obuf, xin, (float*)d_out);
        }
    }
}

// Round 2
// 730.020 us; speedup vs baseline: 1.3280x; 1.3280x over previous
//
#include <hip/hip_runtime.h>
#include <hip/hip_bf16.h>
#include <math.h>

#define NNODES 50000
#define NEDGES 640000
#define DIM    128
#define PEDIM  37
#define KTOT   165   // DIM + PEDIM
#define KPAD   200   // bf16 LDS/global row stride (400 B: 16B-aligned, 2-way banks)
#define NLAYERS 3

using bf16x8 = __attribute__((ext_vector_type(8))) short;
using f32x4  = __attribute__((ext_vector_type(4))) float;

static constexpr size_t alignup(size_t x) { return (x + 255) & ~size_t(255); }
static constexpr size_t OFF_X    = 0;
static constexpr size_t OFF_H    = alignup(OFF_X   + (size_t)NNODES * DIM * 4);
static constexpr size_t OFF_O    = alignup(OFF_H   + (size_t)NNODES * DIM * 4);
static constexpr size_t OFF_HL   = alignup(OFF_O   + (size_t)NNODES * DIM * 4);
static constexpr size_t OFF_HR   = alignup(OFF_HL  + (size_t)NNODES * 4);
static constexpr size_t OFF_OFFS = alignup(OFF_HR  + (size_t)NNODES * 4);
static constexpr size_t OFF_CUR  = alignup(OFF_OFFS + (size_t)(NNODES + 1) * 4);
static constexpr size_t OFF_CSR  = alignup(OFF_CUR + (size_t)NNODES * 4);
static constexpr size_t OFF_BTG  = alignup(OFF_CSR + (size_t)NEDGES * 4);
static constexpr size_t OFF_B2   = alignup(OFF_BTG + (size_t)DIM * KPAD * 2);
static constexpr size_t OFF_ET   = alignup(OFF_B2  + (size_t)DIM * 4);
static constexpr size_t OFF_GS   = alignup(OFF_ET  + 16 * 4);
static constexpr size_t OFF_GS2  = alignup(OFF_GS  + (size_t)DIM * 4);
static constexpr size_t WS_NEED  = alignup(OFF_GS2 + (size_t)DIM * 4);

__device__ inline unsigned short f2b(float f) {
    union { float f; unsigned int u; } x; x.f = f;
    unsigned int r = x.u + 0x7FFFu + ((x.u >> 16) & 1u);
    return (unsigned short)(r >> 16);
}
__device__ inline unsigned int pack2(float a, float b) {
    return (unsigned int)f2b(a) | ((unsigned int)f2b(b) << 16);
}

// ---------------- CSR build ----------------

__global__ void k_zero_int(int* __restrict__ p, int n) {
    for (int i = blockIdx.x * blockDim.x + threadIdx.x; i < n; i += gridDim.x * blockDim.x)
        p[i] = 0;
}

__global__ void k_count(const int* __restrict__ dstv, int* __restrict__ cnt) {
    for (int e = blockIdx.x * blockDim.x + threadIdx.x; e < NEDGES; e += gridDim.x * blockDim.x)
        atomicAdd(&cnt[dstv[e]], 1);
}

__global__ __launch_bounds__(1024) void k_scan(int* __restrict__ cnt_cur, int* __restrict__ offs) {
    __shared__ int sums[1024];
    const int t = threadIdx.x;
    const int CH = (NNODES + 1023) / 1024;
    const int lo = t * CH;
    const int hi = (lo + CH < NNODES) ? lo + CH : NNODES;
    int s = 0;
    for (int i = lo; i < hi; ++i) s += cnt_cur[i];
    sums[t] = s;
    __syncthreads();
    for (int d = 1; d < 1024; d <<= 1) {
        int v = (t >= d) ? sums[t - d] : 0;
        __syncthreads();
        sums[t] += v;
        __syncthreads();
    }
    int run = (t == 0) ? 0 : sums[t - 1];
    for (int i = lo; i < hi; ++i) {
        int c = cnt_cur[i];
        offs[i] = run;
        cnt_cur[i] = run;
        run += c;
    }
    if (t == 1023) offs[NNODES] = sums[1023];
}

__global__ void k_fill(const int* __restrict__ srcv, const int* __restrict__ dstv,
                       const int* __restrict__ attr, int* __restrict__ cur,
                       int* __restrict__ csr) {
    for (int e = blockIdx.x * blockDim.x + threadIdx.x; e < NEDGES; e += gridDim.x * blockDim.x) {
        int d = dstv[e];
        int pos = atomicAdd(&cur[d], 1);
        csr[pos] = (srcv[e] & 0xFFFF) | (attr[e] << 16);
    }
}

// ---------------- per-layer parameter prep ----------------
// Btg[n=128][KPAD] bf16: Btg[n][k] = (k<128 ? linW[k][n] : k<165 ? (peW@linW)[k-128][n] : 0)
// b2 = pe_b @ linW. et[t] = dot(edge_emb[t], attn_e). Zero BN accumulators.
__global__ __launch_bounds__(512) void k_params(
    const float* __restrict__ linW, const float* __restrict__ peW,
    const float* __restrict__ peb, const float* __restrict__ attn_e,
    const float* __restrict__ edge_emb,
    unsigned short* __restrict__ Btg, float* __restrict__ b2, float* __restrict__ et,
    float* __restrict__ gsum, float* __restrict__ gsumsq) {
    const int tid = threadIdx.x;
    const int j = tid & 127;   // output column n
    const int q = tid >> 7;    // 0..3
    for (int k = q; k < KPAD; k += 4) {
        float v = 0.f;
        if (k < DIM) {
            v = linW[k * DIM + j];
        } else if (k < KTOT) {
            const int p = k - DIM;
            float s = 0.f;
            #pragma unroll 8
            for (int d = 0; d < DIM; ++d) s += peW[p * DIM + d] * linW[d * DIM + j];
            v = s;
        }
        Btg[(size_t)j * KPAD + k] = f2b(v);
    }
    if (q == 0) {
        float s = 0.f;
        #pragma unroll 8
        for (int d = 0; d < DIM; ++d) s += peb[d] * linW[d * DIM + j];
        b2[j] = s;
    }
    if (tid < 9) {
        float s = 0.f;
        #pragma unroll 8
        for (int d = 0; d < DIM; ++d) s += edge_emb[tid * DIM + d] * attn_e[d];
        et[tid] = s;
    }
    if (tid < DIM) { gsum[tid] = 0.f; gsumsq[tid] = 0.f; }
}

// ---------------- MFMA GEMM: h = [x|PE] @ B + b2, plus hl/hr ----------------
// BM=64 rows/block, full N=128, K padded to 192 (6 steps of 32). 4 waves: wave w
// owns rows [16w,16w+16). A,Bt in LDS with row stride KPAD=200 bf16 (400 B).
__global__ __launch_bounds__(256) void k_gemm(
    const float* __restrict__ X, const float* __restrict__ PE,
    const unsigned short* __restrict__ Btg, const float* __restrict__ b2,
    const float* __restrict__ attn_l, const float* __restrict__ attn_r,
    float* __restrict__ H, float* __restrict__ HL, float* __restrict__ HR) {
    __shared__ unsigned short Als[64 * KPAD];    // 25.6 KB
    __shared__ unsigned short Bls[DIM * KPAD];   // 51.2 KB
    const int tid = threadIdx.x;
    const int row0 = blockIdx.x * 64;

    // stage B (already bf16, already padded/laid out): 3200 x 16B
    {
        const int4* s = (const int4*)Btg;
        int4* d = (int4*)Bls;
        for (int i = tid; i < DIM * KPAD / 8; i += 256) d[i] = s[i];
    }
    // stage A: 64 rows x 25 chunks of 8 bf16
    for (int ci = tid; ci < 64 * 25; ci += 256) {
        const int r = ci / 25, kc = ci % 25;
        const int gr = row0 + r;
        int4 pk = {0, 0, 0, 0};
        if (gr < NNODES) {
            if (kc < 16) {   // k = 8kc..8kc+7 from X (row is 512B-aligned)
                const float4* xp = (const float4*)&X[(size_t)gr * DIM + kc * 8];
                const float4 v0 = xp[0], v1 = xp[1];
                pk.x = pack2(v0.x, v0.y); pk.y = pack2(v0.z, v0.w);
                pk.z = pack2(v1.x, v1.y); pk.w = pack2(v1.z, v1.w);
            } else {         // k = 128..164 from PE, rest zero
                float f[8];
                #pragma unroll
                for (int i = 0; i < 8; ++i) {
                    const int k = kc * 8 + i;
                    f[i] = (k < KTOT) ? PE[(size_t)gr * PEDIM + (k - DIM)] : 0.f;
                }
                pk.x = pack2(f[0], f[1]); pk.y = pack2(f[2], f[3]);
                pk.z = pack2(f[4], f[5]); pk.w = pack2(f[6], f[7]);
            }
        }
        ((int4*)(Als + (size_t)r * KPAD))[kc] = pk;
    }
    __syncthreads();

    const int w = tid >> 6, l = tid & 63;
    const int c = l & 15;     // A-row-in-tile / B-col / D-col
    const int g = l >> 4;     // k-subgroup (0..3) / D-row-group
    f32x4 zero4 = {0.f, 0.f, 0.f, 0.f};
    f32x4 acc[8];
    #pragma unroll
    for (int t = 0; t < 8; ++t) acc[t] = zero4;

    const unsigned short* aRow = Als + (size_t)(w * 16 + c) * KPAD + g * 8;
    #pragma unroll
    for (int s = 0; s < 6; ++s) {
        const bf16x8 a = *(const bf16x8*)(aRow + s * 32);
        #pragma unroll
        for (int t = 0; t < 8; ++t) {
            const bf16x8 b = *(const bf16x8*)(Bls + (size_t)(t * 16 + c) * KPAD + s * 32 + g * 8);
            acc[t] = __builtin_amdgcn_mfma_f32_16x16x32_bf16(a, b, acc[t], 0, 0, 0);
        }
    }

    float b2v[8], alv[8], arv[8];
    #pragma unroll
    for (int t = 0; t < 8; ++t) {
        b2v[t] = b2[t * 16 + c];
        alv[t] = attn_l[t * 16 + c];
        arv[t] = attn_r[t * 16 + c];
    }
    #pragma unroll
    for (int j = 0; j < 4; ++j) {
        const int grow = row0 + w * 16 + g * 4 + j;
        float vals[8];
        float sl = 0.f, sr = 0.f;
        #pragma unroll
        for (int t = 0; t < 8; ++t) {
            const float v = acc[t][j] + b2v[t];
            vals[t] = v;
            sl = fmaf(v, alv[t], sl);
            sr = fmaf(v, arv[t], sr);
        }
        #pragma unroll
        for (int m = 1; m < 16; m <<= 1) {
            sl += __shfl_xor(sl, m, 64);
            sr += __shfl_xor(sr, m, 64);
        }
        if (grow < NNODES) {
            #pragma unroll
            for (int t = 0; t < 8; ++t) H[(size_t)grow * DIM + t * 16 + c] = vals[t];
            if (c == 0) { HL[grow] = sl; HR[grow] = sr; }
        }
    }
}

// ---------------- per-node softmax + aggregation ----------------
// One wave per node; accumulation uses 4 edge-groups x 16 lanes (32B of row each).
__global__ __launch_bounds__(256) void k_agg(
    const int* __restrict__ offs, const int* __restrict__ csr,
    const float* __restrict__ HL, const float* __restrict__ HR,
    const float* __restrict__ et, const float* __restrict__ H,
    const float* __restrict__ bias, float* __restrict__ OUT) {
    const int lane = threadIdx.x & 63;
    const int node = blockIdx.x * 4 + (threadIdx.x >> 6);
    if (node >= NNODES) return;
    const int off0 = offs[node];
    const int deg = offs[node + 1] - off0;

    const float hri = HR[node];
    float myA = 0.f;
    int myE = 0;
    float mx = -1e30f;
    for (int j = lane; j < deg; j += 64) {
        const int en = csr[off0 + j];
        float al = HL[en & 0xFFFF] + hri + et[en >> 16];
        al = al > 0.f ? al : 0.2f * al;
        if (j < 64) { myA = al; myE = en; }
        mx = fmaxf(mx, al);
    }
    #pragma unroll
    for (int m = 1; m < 64; m <<= 1) mx = fmaxf(mx, __shfl_xor(mx, m, 64));

    float s = 0.f, wv = 0.f;
    if (deg <= 64) {
        wv = (lane < deg) ? __expf(myA - mx) : 0.f;
        s = wv;
    } else {
        for (int j = lane; j < deg; j += 64) {
            const int en = csr[off0 + j];
            float al = HL[en & 0xFFFF] + hri + et[en >> 16];
            al = al > 0.f ? al : 0.2f * al;
            s += __expf(al - mx);
        }
    }
    #pragma unroll
    for (int m = 1; m < 64; m <<= 1) s += __shfl_xor(s, m, 64);
    const float invd = (deg > 0) ? 1.f / s : 0.f;
    wv *= invd;

    // accumulation: edge-group eg = lane>>4 handles edges jb+eg; 16 lanes cover row
    const int eg = lane >> 4, c = lane & 15;
    float4 a0 = {0.f, 0.f, 0.f, 0.f}, a1 = {0.f, 0.f, 0.f, 0.f};
    for (int jb = 0; jb < deg; jb += 4) {
        const int j = jb + eg;
        const bool valid = j < deg;
        float wgt = 0.f;
        int src = 0;
        if (deg <= 64) {
            wgt = __shfl(wv, j & 63, 64);
            src = __shfl(myE, j & 63, 64) & 0xFFFF;
            if (!valid) wgt = 0.f;
        } else if (valid) {
            const int en = csr[off0 + j];
            float al = HL[en & 0xFFFF] + hri + et[en >> 16];
            al = al > 0.f ? al : 0.2f * al;
            wgt = __expf(al - mx) * invd;
            src = en & 0xFFFF;
        }
        if (valid) {
            const float4* hp = (const float4*)&H[(size_t)src * DIM + c * 8];
            const float4 h0 = hp[0], h1 = hp[1];
            a0.x = fmaf(wgt, h0.x, a0.x); a0.y = fmaf(wgt, h0.y, a0.y);
            a0.z = fmaf(wgt, h0.z, a0.z); a0.w = fmaf(wgt, h0.w, a0.w);
            a1.x = fmaf(wgt, h1.x, a1.x); a1.y = fmaf(wgt, h1.y, a1.y);
            a1.z = fmaf(wgt, h1.z, a1.z); a1.w = fmaf(wgt, h1.w, a1.w);
        }
    }
    // reduce across the 4 edge-groups (lanes differing in bits 4,5)
    #pragma unroll
    for (int m = 16; m < 64; m <<= 1) {
        a0.x += __shfl_xor(a0.x, m, 64); a0.y += __shfl_xor(a0.y, m, 64);
        a0.z += __shfl_xor(a0.z, m, 64); a0.w += __shfl_xor(a0.w, m, 64);
        a1.x += __shfl_xor(a1.x, m, 64); a1.y += __shfl_xor(a1.y, m, 64);
        a1.z += __shfl_xor(a1.z, m, 64); a1.w += __shfl_xor(a1.w, m, 64);
    }
    if (eg == 0) {
        float4 b0 = *(const float4*)&bias[c * 8];
        float4 b1 = *(const float4*)&bias[c * 8 + 4];
        a0.x += b0.x; a0.y += b0.y; a0.z += b0.z; a0.w += b0.w;
        a1.x += b1.x; a1.y += b1.y; a1.z += b1.z; a1.w += b1.w;
        float4* op = (float4*)&OUT[(size_t)node * DIM + c * 8];
        op[0] = a0; op[1] = a1;
    }
}

// ---------------- BN stats ----------------
__global__ __launch_bounds__(256) void k_bnstats(
    const float* __restrict__ OUT, float* __restrict__ gsum, float* __restrict__ gsumsq) {
    __shared__ float ls[256], ls2[256];
    const int c = threadIdx.x & 127;
    const int half = threadIdx.x >> 7;
    const int rend = min(NNODES, (int)(blockIdx.x * 256 + 256));
    float s = 0.f, s2 = 0.f;
    for (int r = blockIdx.x * 256 + half; r < rend; r += 2) {
        const float v = OUT[(size_t)r * DIM + c];
        s += v;
        s2 = fmaf(v, v, s2);
    }
    ls[threadIdx.x] = s;
    ls2[threadIdx.x] = s2;
    __syncthreads();
    if (half == 0) {
        atomicAdd(&gsum[c], ls[c] + ls[c + 128]);
        atomicAdd(&gsumsq[c], ls2[c] + ls2[c + 128]);
    }
}

// ---------------- apply BN + residual ----------------
__global__ __launch_bounds__(256) void k_apply_bn(
    const float* __restrict__ OUT, const float* __restrict__ XPREV,
    const float* __restrict__ gsum, const float* __restrict__ gsumsq,
    const float* __restrict__ gamma, const float* __restrict__ beta,
    float* __restrict__ XNEXT) {
    const int idx = blockIdx.x * 256 + threadIdx.x;
    const int c = idx & 127;
    const float mu = gsum[c] * (1.f / NNODES);
    const float var = gsumsq[c] * (1.f / NNODES) - mu * mu;
    const float sc = gamma[c] * rsqrtf(var + 1e-5f);
    XNEXT[idx] = (OUT[idx] - mu) * sc + beta[c] + XPREV[idx];
}

__global__ __launch_bounds__(256) void k_apply_last(
    const float* __restrict__ OUT, const float* __restrict__ XPREV, float* __restrict__ XF) {
    const int idx = blockIdx.x * 256 + threadIdx.x;
    XF[idx] = OUT[idx] + XPREV[idx];
}

// ---------------- host ----------------
extern "C" void kernel_launch(void* const* d_in, const int* in_sizes, int n_in,
                              void* d_out, int out_size, void* d_ws, size_t ws_size,
                              hipStream_t stream) {
    const float* X_n      = (const float*)d_in[0];
    const float* PE       = (const float*)d_in[1];
    const int*   eidx     = (const int*)d_in[2];
    const int*   eattr    = (const int*)d_in[3];
    const float* edge_emb = (const float*)d_in[4];
    const float* pe_W     = (const float*)d_in[5];
    const float* pe_b     = (const float*)d_in[6];
    const float* lin_W    = (const float*)d_in[7];
    const float* attn_l   = (const float*)d_in[8];
    const float* attn_r   = (const float*)d_in[9];
    const float* attn_e   = (const float*)d_in[10];
    const float* bias     = (const float*)d_in[11];
    const float* bng      = (const float*)d_in[12];
    const float* bnb      = (const float*)d_in[13];

    if (ws_size < WS_NEED) return;

    char* ws = (char*)d_ws;
    float* xbuf   = (float*)(ws + OFF_X);
    float* hbuf   = (float*)(ws + OFF_H);
    float* obuf   = (float*)(ws + OFF_O);
    float* hl     = (float*)(ws + OFF_HL);
    float* hr     = (float*)(ws + OFF_HR);
    int*   offs   = (int*)(ws + OFF_OFFS);
    int*   cur    = (int*)(ws + OFF_CUR);
    int*   csr    = (int*)(ws + OFF_CSR);
    unsigned short* Btg = (unsigned short*)(ws + OFF_BTG);
    float* b2     = (float*)(ws + OFF_B2);
    float* et     = (float*)(ws + OFF_ET);
    float* gsum   = (float*)(ws + OFF_GS);
    float* gsumsq = (float*)(ws + OFF_GS2);

    const int* srcv = eidx;
    const int* dstv = eidx + NEDGES;

    hipLaunchKernelGGL(k_zero_int, dim3(256), dim3(256), 0, stream, cur, NNODES);
    hipLaunchKernelGGL(k_count, dim3(1024), dim3(256), 0, stream, dstv, cur);
    hipLaunchKernelGGL(k_scan, dim3(1), dim3(1024), 0, stream, cur, offs);
    hipLaunchKernelGGL(k_fill, dim3(1024), dim3(256), 0, stream, srcv, dstv, eattr, cur, csr);

    const float* xin = X_n;
    for (int l = 0; l < NLAYERS; ++l) {
        hipLaunchKernelGGL(k_params, dim3(1), dim3(512), 0, stream,
                           lin_W + (size_t)l * DIM * DIM, pe_W + (size_t)l * PEDIM * DIM,
                           pe_b + (size_t)l * DIM, attn_e + (size_t)l * DIM,
                           edge_emb + (size_t)l * 9 * DIM,
                           Btg, b2, et, gsum, gsumsq);
        hipLaunchKernelGGL(k_gemm, dim3((NNODES + 63) / 64), dim3(256), 0, stream,
                           xin, PE, Btg, b2, attn_l + (size_t)l * DIM, attn_r + (size_t)l * DIM,
                           hbuf, hl, hr);
        hipLaunchKernelGGL(k_agg, dim3((NNODES + 3) / 4), dim3(256), 0, stream,
                           offs, csr, hl, hr, et, hbuf, bias + (size_t)l * DIM, obuf);
        if (l < NLAYERS - 1) {
            hipLaunchKernelGGL(k_bnstats, dim3((NNODES + 255) / 256), dim3(256), 0, stream,
                               obuf, gsum, gsumsq);
            hipLaunchKernelGGL(k_apply_bn, dim3(NNODES * DIM / 256), dim3(256), 0, stream,
                               obuf, xin, gsum, gsumsq, bng + (size_t)l * DIM, bnb + (size_t)l * DIM,
                               xbuf);
            xin = xbuf;
        } else {
            hipLaunchKernelGGL(k_apply_last, dim3(NNODES * DIM / 256), dim3(256), 0, stream,
                               obuf, xin, (float*)d_out);
        }
    }
}

// Round 3
// 445.375 us; speedup vs baseline: 2.1767x; 1.6391x over previous
//
#include <hip/hip_runtime.h>
#include <hip/hip_bf16.h>
#include <math.h>

#define NNODES 50000
#define NEDGES 640000
#define DIM    128
#define PEDIM  37
#define KTOT   165   // DIM + PEDIM
#define KPAD   200   // bf16 LDS/global row stride (400 B: 16B-aligned, 2-way banks)
#define NLAYERS 3
#define NSB    ((NNODES + 255) / 256)   // 196 scan blocks

using bf16x8 = __attribute__((ext_vector_type(8))) short;
using f32x4  = __attribute__((ext_vector_type(4))) float;

static constexpr size_t alignup(size_t x) { return (x + 255) & ~size_t(255); }
static constexpr size_t OFF_X    = 0;
static constexpr size_t OFF_H    = alignup(OFF_X   + (size_t)NNODES * DIM * 4);
static constexpr size_t OFF_O    = alignup(OFF_H   + (size_t)NNODES * DIM * 4);
static constexpr size_t OFF_HL   = alignup(OFF_O   + (size_t)NNODES * DIM * 4);
static constexpr size_t OFF_HR   = alignup(OFF_HL  + (size_t)NNODES * 4);
static constexpr size_t OFF_OFFS = alignup(OFF_HR  + (size_t)NNODES * 4);
static constexpr size_t OFF_CUR  = alignup(OFF_OFFS + (size_t)(NNODES + 1) * 4);
static constexpr size_t OFF_CSR  = alignup(OFF_CUR + (size_t)NNODES * 4);
static constexpr size_t OFF_BTG  = alignup(OFF_CSR + (size_t)NEDGES * 4);
static constexpr size_t OFF_B2   = alignup(OFF_BTG + (size_t)DIM * KPAD * 2);
static constexpr size_t OFF_ET   = alignup(OFF_B2  + (size_t)DIM * 4);
static constexpr size_t OFF_GS   = alignup(OFF_ET  + 16 * 4);
static constexpr size_t OFF_GS2  = alignup(OFF_GS  + (size_t)DIM * 4);
static constexpr size_t OFF_BS   = alignup(OFF_GS2 + (size_t)DIM * 4);
static constexpr size_t OFF_BP   = alignup(OFF_BS  + 256 * 4);
static constexpr size_t WS_NEED  = alignup(OFF_BP  + 256 * 4);

__device__ inline unsigned short f2b(float f) {
    union { float f; unsigned int u; } x; x.f = f;
    unsigned int r = x.u + 0x7FFFu + ((x.u >> 16) & 1u);
    return (unsigned short)(r >> 16);
}
__device__ inline unsigned int pack2(float a, float b) {
    return (unsigned int)f2b(a) | ((unsigned int)f2b(b) << 16);
}

// ---------------- CSR build ----------------

__global__ void k_zero_int(int* __restrict__ p, int n) {
    for (int i = blockIdx.x * blockDim.x + threadIdx.x; i < n; i += gridDim.x * blockDim.x)
        p[i] = 0;
}

__global__ void k_count(const int* __restrict__ dstv, int* __restrict__ cnt) {
    for (int e = blockIdx.x * blockDim.x + threadIdx.x; e < NEDGES; e += gridDim.x * blockDim.x)
        atomicAdd(&cnt[dstv[e]], 1);
}

// phase 1: per-256-chunk sums
__global__ __launch_bounds__(256) void k_scan1(const int* __restrict__ cnt, int* __restrict__ bsum) {
    __shared__ int ls[256];
    const int i = blockIdx.x * 256 + threadIdx.x;
    ls[threadIdx.x] = (i < NNODES) ? cnt[i] : 0;
    __syncthreads();
    for (int d = 128; d > 0; d >>= 1) {
        if (threadIdx.x < d) ls[threadIdx.x] += ls[threadIdx.x + d];
        __syncthreads();
    }
    if (threadIdx.x == 0) bsum[blockIdx.x] = ls[0];
}

// phase 2: scan the NSB block sums (1 block)
__global__ __launch_bounds__(256) void k_scan2(const int* __restrict__ bsum,
                                               int* __restrict__ bpre, int* __restrict__ offs) {
    __shared__ int ls[256];
    const int t = threadIdx.x;
    ls[t] = (t < NSB) ? bsum[t] : 0;
    __syncthreads();
    for (int d = 1; d < 256; d <<= 1) {
        int v = (t >= d) ? ls[t - d] : 0;
        __syncthreads();
        ls[t] += v;
        __syncthreads();
    }
    bpre[t] = (t == 0) ? 0 : ls[t - 1];
    if (t == 255) offs[NNODES] = ls[255];
}

// phase 3: in-block exclusive scan + block prefix -> offs, cur
__global__ __launch_bounds__(256) void k_scan3(const int* __restrict__ cnt,
                                               const int* __restrict__ bpre,
                                               int* __restrict__ offs, int* __restrict__ cur) {
    __shared__ int ls[256];
    const int i = blockIdx.x * 256 + threadIdx.x;
    const int v = (i < NNODES) ? cnt[i] : 0;
    ls[threadIdx.x] = v;
    __syncthreads();
    for (int d = 1; d < 256; d <<= 1) {
        int x = (threadIdx.x >= d) ? ls[threadIdx.x - d] : 0;
        __syncthreads();
        ls[threadIdx.x] += x;
        __syncthreads();
    }
    if (i < NNODES) {
        const int excl = ls[threadIdx.x] - v + bpre[blockIdx.x];
        offs[i] = excl;
        cur[i] = excl;
    }
}

__global__ void k_fill(const int* __restrict__ srcv, const int* __restrict__ dstv,
                       const int* __restrict__ attr, int* __restrict__ cur,
                       int* __restrict__ csr) {
    for (int e = blockIdx.x * blockDim.x + threadIdx.x; e < NEDGES; e += gridDim.x * blockDim.x) {
        int d = dstv[e];
        int pos = atomicAdd(&cur[d], 1);
        csr[pos] = (srcv[e] & 0xFFFF) | (attr[e] << 16);
    }
}

// ---------------- per-layer parameter prep (parallel) ----------------
// grid = 101 blocks x 256. Blocks 0..99: Btg[j][k] (transpose+bf16, rows>=128 are peW@linW).
// Block 100: b2 = pe_b@linW, et[t] = dot(edge_emb[t], attn_e), zero BN accumulators.
__global__ __launch_bounds__(256) void k_params(
    const float* __restrict__ linW, const float* __restrict__ peW,
    const float* __restrict__ peb, const float* __restrict__ attn_e,
    const float* __restrict__ edge_emb,
    unsigned short* __restrict__ Btg, float* __restrict__ b2, float* __restrict__ et,
    float* __restrict__ gsum, float* __restrict__ gsumsq) {
    if (blockIdx.x < 100) {
        const int idx = blockIdx.x * 256 + threadIdx.x;   // 0..25599
        const int j = idx & 127;
        const int k = idx >> 7;                            // 0..199
        float v = 0.f;
        if (k < DIM) {
            v = linW[k * DIM + j];
        } else if (k < KTOT) {
            const int p = k - DIM;
            float s = 0.f;
            #pragma unroll 8
            for (int d = 0; d < DIM; ++d) s = fmaf(peW[p * DIM + d], linW[d * DIM + j], s);
            v = s;
        }
        Btg[(size_t)j * KPAD + k] = f2b(v);
    } else {
        const int t = threadIdx.x;
        if (t < DIM) {
            float s = 0.f;
            #pragma unroll 8
            for (int d = 0; d < DIM; ++d) s = fmaf(peb[d], linW[d * DIM + t], s);
            b2[t] = s;
            gsum[t] = 0.f;
            gsumsq[t] = 0.f;
        } else if (t < DIM + 9) {
            const int e = t - DIM;
            float s = 0.f;
            #pragma unroll 8
            for (int d = 0; d < DIM; ++d) s = fmaf(edge_emb[e * DIM + d], attn_e[d], s);
            et[e] = s;
        }
    }
}

// ---------------- MFMA GEMM: h = [x|PE] @ B + b2, plus hl/hr ----------------
__global__ __launch_bounds__(256) void k_gemm(
    const float* __restrict__ X, const float* __restrict__ PE,
    const unsigned short* __restrict__ Btg, const float* __restrict__ b2,
    const float* __restrict__ attn_l, const float* __restrict__ attn_r,
    float* __restrict__ H, float* __restrict__ HL, float* __restrict__ HR) {
    __shared__ unsigned short Als[64 * KPAD];    // 25.6 KB
    __shared__ unsigned short Bls[DIM * KPAD];   // 51.2 KB
    const int tid = threadIdx.x;
    const int row0 = blockIdx.x * 64;

    {
        const int4* s = (const int4*)Btg;
        int4* d = (int4*)Bls;
        for (int i = tid; i < DIM * KPAD / 8; i += 256) d[i] = s[i];
    }
    for (int ci = tid; ci < 64 * 25; ci += 256) {
        const int r = ci / 25, kc = ci % 25;
        const int gr = row0 + r;
        int4 pk = {0, 0, 0, 0};
        if (gr < NNODES) {
            if (kc < 16) {
                const float4* xp = (const float4*)&X[(size_t)gr * DIM + kc * 8];
                const float4 v0 = xp[0], v1 = xp[1];
                pk.x = pack2(v0.x, v0.y); pk.y = pack2(v0.z, v0.w);
                pk.z = pack2(v1.x, v1.y); pk.w = pack2(v1.z, v1.w);
            } else {
                float f[8];
                #pragma unroll
                for (int i = 0; i < 8; ++i) {
                    const int k = kc * 8 + i;
                    f[i] = (k < KTOT) ? PE[(size_t)gr * PEDIM + (k - DIM)] : 0.f;
                }
                pk.x = pack2(f[0], f[1]); pk.y = pack2(f[2], f[3]);
                pk.z = pack2(f[4], f[5]); pk.w = pack2(f[6], f[7]);
            }
        }
        ((int4*)(Als + (size_t)r * KPAD))[kc] = pk;
    }
    __syncthreads();

    const int w = tid >> 6, l = tid & 63;
    const int c = l & 15;
    const int g = l >> 4;
    f32x4 zero4 = {0.f, 0.f, 0.f, 0.f};
    f32x4 acc[8];
    #pragma unroll
    for (int t = 0; t < 8; ++t) acc[t] = zero4;

    const unsigned short* aRow = Als + (size_t)(w * 16 + c) * KPAD + g * 8;
    #pragma unroll
    for (int s = 0; s < 6; ++s) {
        const bf16x8 a = *(const bf16x8*)(aRow + s * 32);
        #pragma unroll
        for (int t = 0; t < 8; ++t) {
            const bf16x8 b = *(const bf16x8*)(Bls + (size_t)(t * 16 + c) * KPAD + s * 32 + g * 8);
            acc[t] = __builtin_amdgcn_mfma_f32_16x16x32_bf16(a, b, acc[t], 0, 0, 0);
        }
    }

    float b2v[8], alv[8], arv[8];
    #pragma unroll
    for (int t = 0; t < 8; ++t) {
        b2v[t] = b2[t * 16 + c];
        alv[t] = attn_l[t * 16 + c];
        arv[t] = attn_r[t * 16 + c];
    }
    #pragma unroll
    for (int j = 0; j < 4; ++j) {
        const int grow = row0 + w * 16 + g * 4 + j;
        float vals[8];
        float sl = 0.f, sr = 0.f;
        #pragma unroll
        for (int t = 0; t < 8; ++t) {
            const float v = acc[t][j] + b2v[t];
            vals[t] = v;
            sl = fmaf(v, alv[t], sl);
            sr = fmaf(v, arv[t], sr);
        }
        #pragma unroll
        for (int m = 1; m < 16; m <<= 1) {
            sl += __shfl_xor(sl, m, 64);
            sr += __shfl_xor(sr, m, 64);
        }
        if (grow < NNODES) {
            #pragma unroll
            for (int t = 0; t < 8; ++t) H[(size_t)grow * DIM + t * 16 + c] = vals[t];
            if (c == 0) { HL[grow] = sl; HR[grow] = sr; }
        }
    }
}

// ---------------- per-node softmax + aggregation ----------------
__global__ __launch_bounds__(256) void k_agg(
    const int* __restrict__ offs, const int* __restrict__ csr,
    const float* __restrict__ HL, const float* __restrict__ HR,
    const float* __restrict__ et, const float* __restrict__ H,
    const float* __restrict__ bias, float* __restrict__ OUT) {
    const int lane = threadIdx.x & 63;
    const int node = blockIdx.x * 4 + (threadIdx.x >> 6);
    if (node >= NNODES) return;
    const int off0 = offs[node];
    const int deg = offs[node + 1] - off0;

    const float hri = HR[node];
    float myA = 0.f;
    int myE = 0;
    float mx = -1e30f;
    for (int j = lane; j < deg; j += 64) {
        const int en = csr[off0 + j];
        float al = HL[en & 0xFFFF] + hri + et[en >> 16];
        al = al > 0.f ? al : 0.2f * al;
        if (j < 64) { myA = al; myE = en; }
        mx = fmaxf(mx, al);
    }
    #pragma unroll
    for (int m = 1; m < 64; m <<= 1) mx = fmaxf(mx, __shfl_xor(mx, m, 64));

    float s = 0.f, wv = 0.f;
    if (deg <= 64) {
        wv = (lane < deg) ? __expf(myA - mx) : 0.f;
        s = wv;
    } else {
        for (int j = lane; j < deg; j += 64) {
            const int en = csr[off0 + j];
            float al = HL[en & 0xFFFF] + hri + et[en >> 16];
            al = al > 0.f ? al : 0.2f * al;
            s += __expf(al - mx);
        }
    }
    #pragma unroll
    for (int m = 1; m < 64; m <<= 1) s += __shfl_xor(s, m, 64);
    const float invd = (deg > 0) ? 1.f / s : 0.f;
    wv *= invd;

    const int eg = lane >> 4, c = lane & 15;
    float4 a0 = {0.f, 0.f, 0.f, 0.f}, a1 = {0.f, 0.f, 0.f, 0.f};
    for (int jb = 0; jb < deg; jb += 4) {
        const int j = jb + eg;
        const bool valid = j < deg;
        float wgt = 0.f;
        int src = 0;
        if (deg <= 64) {
            wgt = __shfl(wv, j & 63, 64);
            src = __shfl(myE, j & 63, 64) & 0xFFFF;
            if (!valid) wgt = 0.f;
        } else if (valid) {
            const int en = csr[off0 + j];
            float al = HL[en & 0xFFFF] + hri + et[en >> 16];
            al = al > 0.f ? al : 0.2f * al;
            wgt = __expf(al - mx) * invd;
            src = en & 0xFFFF;
        }
        if (valid) {
            const float4* hp = (const float4*)&H[(size_t)src * DIM + c * 8];
            const float4 h0 = hp[0], h1 = hp[1];
            a0.x = fmaf(wgt, h0.x, a0.x); a0.y = fmaf(wgt, h0.y, a0.y);
            a0.z = fmaf(wgt, h0.z, a0.z); a0.w = fmaf(wgt, h0.w, a0.w);
            a1.x = fmaf(wgt, h1.x, a1.x); a1.y = fmaf(wgt, h1.y, a1.y);
            a1.z = fmaf(wgt, h1.z, a1.z); a1.w = fmaf(wgt, h1.w, a1.w);
        }
    }
    #pragma unroll
    for (int m = 16; m < 64; m <<= 1) {
        a0.x += __shfl_xor(a0.x, m, 64); a0.y += __shfl_xor(a0.y, m, 64);
        a0.z += __shfl_xor(a0.z, m, 64); a0.w += __shfl_xor(a0.w, m, 64);
        a1.x += __shfl_xor(a1.x, m, 64); a1.y += __shfl_xor(a1.y, m, 64);
        a1.z += __shfl_xor(a1.z, m, 64); a1.w += __shfl_xor(a1.w, m, 64);
    }
    if (eg == 0) {
        float4 b0 = *(const float4*)&bias[c * 8];
        float4 b1 = *(const float4*)&bias[c * 8 + 4];
        a0.x += b0.x; a0.y += b0.y; a0.z += b0.z; a0.w += b0.w;
        a1.x += b1.x; a1.y += b1.y; a1.z += b1.z; a1.w += b1.w;
        float4* op = (float4*)&OUT[(size_t)node * DIM + c * 8];
        op[0] = a0; op[1] = a1;
    }
}

// ---------------- BN stats ----------------
__global__ __launch_bounds__(256) void k_bnstats(
    const float* __restrict__ OUT, float* __restrict__ gsum, float* __restrict__ gsumsq) {
    __shared__ float ls[256], ls2[256];
    const int c = threadIdx.x & 127;
    const int half = threadIdx.x >> 7;
    const int rend = min(NNODES, (int)(blockIdx.x * 256 + 256));
    float s = 0.f, s2 = 0.f;
    for (int r = blockIdx.x * 256 + half; r < rend; r += 2) {
        const float v = OUT[(size_t)r * DIM + c];
        s += v;
        s2 = fmaf(v, v, s2);
    }
    ls[threadIdx.x] = s;
    ls2[threadIdx.x] = s2;
    __syncthreads();
    if (half == 0) {
        atomicAdd(&gsum[c], ls[c] + ls[c + 128]);
        atomicAdd(&gsumsq[c], ls2[c] + ls2[c + 128]);
    }
}

// ---------------- apply BN + residual ----------------
__global__ __launch_bounds__(256) void k_apply_bn(
    const float* __restrict__ OUT, const float* __restrict__ XPREV,
    const float* __restrict__ gsum, const float* __restrict__ gsumsq,
    const float* __restrict__ gamma, const float* __restrict__ beta,
    float* __restrict__ XNEXT) {
    const int idx = blockIdx.x * 256 + threadIdx.x;
    const int c = idx & 127;
    const float mu = gsum[c] * (1.f / NNODES);
    const float var = gsumsq[c] * (1.f / NNODES) - mu * mu;
    const float sc = gamma[c] * rsqrtf(var + 1e-5f);
    XNEXT[idx] = (OUT[idx] - mu) * sc + beta[c] + XPREV[idx];
}

__global__ __launch_bounds__(256) void k_apply_last(
    const float* __restrict__ OUT, const float* __restrict__ XPREV, float* __restrict__ XF) {
    const int idx = blockIdx.x * 256 + threadIdx.x;
    XF[idx] = OUT[idx] + XPREV[idx];
}

// ---------------- host ----------------
extern "C" void kernel_launch(void* const* d_in, const int* in_sizes, int n_in,
                              void* d_out, int out_size, void* d_ws, size_t ws_size,
                              hipStream_t stream) {
    const float* X_n      = (const float*)d_in[0];
    const float* PE       = (const float*)d_in[1];
    const int*   eidx     = (const int*)d_in[2];
    const int*   eattr    = (const int*)d_in[3];
    const float* edge_emb = (const float*)d_in[4];
    const float* pe_W     = (const float*)d_in[5];
    const float* pe_b     = (const float*)d_in[6];
    const float* lin_W    = (const float*)d_in[7];
    const float* attn_l   = (const float*)d_in[8];
    const float* attn_r   = (const float*)d_in[9];
    const float* attn_e   = (const float*)d_in[10];
    const float* bias     = (const float*)d_in[11];
    const float* bng      = (const float*)d_in[12];
    const float* bnb      = (const float*)d_in[13];

    if (ws_size < WS_NEED) return;

    char* ws = (char*)d_ws;
    float* xbuf   = (float*)(ws + OFF_X);
    float* hbuf   = (float*)(ws + OFF_H);
    float* obuf   = (float*)(ws + OFF_O);
    float* hl     = (float*)(ws + OFF_HL);
    float* hr     = (float*)(ws + OFF_HR);
    int*   offs   = (int*)(ws + OFF_OFFS);
    int*   cur    = (int*)(ws + OFF_CUR);
    int*   csr    = (int*)(ws + OFF_CSR);
    unsigned short* Btg = (unsigned short*)(ws + OFF_BTG);
    float* b2     = (float*)(ws + OFF_B2);
    float* et     = (float*)(ws + OFF_ET);
    float* gsum   = (float*)(ws + OFF_GS);
    float* gsumsq = (float*)(ws + OFF_GS2);
    int*   bsum   = (int*)(ws + OFF_BS);
    int*   bpre   = (int*)(ws + OFF_BP);

    const int* srcv = eidx;
    const int* dstv = eidx + NEDGES;

    hipLaunchKernelGGL(k_zero_int, dim3(256), dim3(256), 0, stream, cur, NNODES);
    hipLaunchKernelGGL(k_count, dim3(1024), dim3(256), 0, stream, dstv, cur);
    hipLaunchKernelGGL(k_scan1, dim3(NSB), dim3(256), 0, stream, cur, bsum);
    hipLaunchKernelGGL(k_scan2, dim3(1), dim3(256), 0, stream, bsum, bpre, offs);
    hipLaunchKernelGGL(k_scan3, dim3(NSB), dim3(256), 0, stream, cur, bpre, offs, cur);
    hipLaunchKernelGGL(k_fill, dim3(1024), dim3(256), 0, stream, srcv, dstv, eattr, cur, csr);

    const float* xin = X_n;
    for (int l = 0; l < NLAYERS; ++l) {
        hipLaunchKernelGGL(k_params, dim3(101), dim3(256), 0, stream,
                           lin_W + (size_t)l * DIM * DIM, pe_W + (size_t)l * PEDIM * DIM,
                           pe_b + (size_t)l * DIM, attn_e + (size_t)l * DIM,
                           edge_emb + (size_t)l * 9 * DIM,
                           Btg, b2, et, gsum, gsumsq);
        hipLaunchKernelGGL(k_gemm, dim3((NNODES + 63) / 64), dim3(256), 0, stream,
                           xin, PE, Btg, b2, attn_l + (size_t)l * DIM, attn_r + (size_t)l * DIM,
                           hbuf, hl, hr);
        hipLaunchKernelGGL(k_agg, dim3((NNODES + 3) / 4), dim3(256), 0, stream,
                           offs, csr, hl, hr, et, hbuf, bias + (size_t)l * DIM, obuf);
        if (l < NLAYERS - 1) {
            hipLaunchKernelGGL(k_bnstats, dim3((NNODES + 255) / 256), dim3(256), 0, stream,
                               obuf, gsum, gsumsq);
            hipLaunchKernelGGL(k_apply_bn, dim3(NNODES * DIM / 256), dim3(256), 0, stream,
                               obuf, xin, gsum, gsumsq, bng + (size_t)l * DIM, bnb + (size_t)l * DIM,
                               xbuf);
            xin = xbuf;
        } else {
            hipLaunchKernelGGL(k_apply_last, dim3(NNODES * DIM / 256), dim3(256), 0, stream,
                               obuf, xin, (float*)d_out);
        }
    }
}

// Round 4
// 374.736 us; speedup vs baseline: 2.5870x; 1.1885x over previous
//
#include <hip/hip_runtime.h>
#include <hip/hip_bf16.h>
#include <math.h>

#define NNODES 50000
#define NEDGES 640000
#define DIM    128
#define PEDIM  37
#define KTOT   165   // DIM + PEDIM
#define KPAD   200   // bf16 row stride for A and B (400 B = 25 int4, 16B-aligned)
#define HSTR   136   // LDS repack stride (272 B, 16B-aligned, conflict-benign)
#define NLAYERS 3
#define NSB    ((NNODES + 255) / 256)   // 196 scan blocks

using bf16x8 = __attribute__((ext_vector_type(8))) short;
using f32x4  = __attribute__((ext_vector_type(4))) float;

static constexpr size_t alignup(size_t x) { return (x + 255) & ~size_t(255); }
static constexpr size_t OFF_X    = 0;                                              // fp32 x (residual), 25.6 MB
static constexpr size_t OFF_H    = alignup(OFF_X   + (size_t)NNODES * DIM * 4);    // bf16 H, 12.8 MB
static constexpr size_t OFF_O    = alignup(OFF_H   + (size_t)NNODES * DIM * 2);    // fp32 out, 25.6 MB
static constexpr size_t OFF_AB   = alignup(OFF_O   + (size_t)NNODES * DIM * 4);    // bf16 A=[x|PE|0], 20 MB
static constexpr size_t OFF_HL   = alignup(OFF_AB  + (size_t)NNODES * KPAD * 2);
static constexpr size_t OFF_HR   = alignup(OFF_HL  + (size_t)NNODES * 4);
static constexpr size_t OFF_OFFS = alignup(OFF_HR  + (size_t)NNODES * 4);
static constexpr size_t OFF_CUR  = alignup(OFF_OFFS + (size_t)(NNODES + 1) * 4);
static constexpr size_t OFF_CSR  = alignup(OFF_CUR + (size_t)NNODES * 4);
static constexpr size_t OFF_BTG  = alignup(OFF_CSR + (size_t)NEDGES * 4);
static constexpr size_t OFF_B2   = alignup(OFF_BTG + (size_t)DIM * KPAD * 2);
static constexpr size_t OFF_ET   = alignup(OFF_B2  + (size_t)DIM * 4);
static constexpr size_t OFF_GS   = alignup(OFF_ET  + 16 * 4);
static constexpr size_t OFF_GS2  = alignup(OFF_GS  + (size_t)DIM * 4);
static constexpr size_t OFF_BS   = alignup(OFF_GS2 + (size_t)DIM * 4);
static constexpr size_t OFF_BP   = alignup(OFF_BS  + 256 * 4);
static constexpr size_t WS_NEED  = alignup(OFF_BP  + 256 * 4);

__device__ inline unsigned short f2b(float f) {
    union { float f; unsigned int u; } x; x.f = f;
    unsigned int r = x.u + 0x7FFFu + ((x.u >> 16) & 1u);
    return (unsigned short)(r >> 16);
}

__device__ inline void gload_lds16(const void* g, void* l) {
    __builtin_amdgcn_global_load_lds((const __attribute__((address_space(1))) void*)g,
                                     (__attribute__((address_space(3))) void*)l, 16, 0, 0);
}

// ---------------- CSR build ----------------

__global__ void k_zero_int(int* __restrict__ p, int n) {
    for (int i = blockIdx.x * blockDim.x + threadIdx.x; i < n; i += gridDim.x * blockDim.x)
        p[i] = 0;
}

__global__ void k_count(const int* __restrict__ dstv, int* __restrict__ cnt) {
    for (int e = blockIdx.x * blockDim.x + threadIdx.x; e < NEDGES; e += gridDim.x * blockDim.x)
        atomicAdd(&cnt[dstv[e]], 1);
}

__global__ __launch_bounds__(256) void k_scan1(const int* __restrict__ cnt, int* __restrict__ bsum) {
    __shared__ int ls[256];
    const int i = blockIdx.x * 256 + threadIdx.x;
    ls[threadIdx.x] = (i < NNODES) ? cnt[i] : 0;
    __syncthreads();
    for (int d = 128; d > 0; d >>= 1) {
        if (threadIdx.x < d) ls[threadIdx.x] += ls[threadIdx.x + d];
        __syncthreads();
    }
    if (threadIdx.x == 0) bsum[blockIdx.x] = ls[0];
}

__global__ __launch_bounds__(256) void k_scan2(const int* __restrict__ bsum,
                                               int* __restrict__ bpre, int* __restrict__ offs) {
    __shared__ int ls[256];
    const int t = threadIdx.x;
    ls[t] = (t < NSB) ? bsum[t] : 0;
    __syncthreads();
    for (int d = 1; d < 256; d <<= 1) {
        int v = (t >= d) ? ls[t - d] : 0;
        __syncthreads();
        ls[t] += v;
        __syncthreads();
    }
    bpre[t] = (t == 0) ? 0 : ls[t - 1];
    if (t == 255) offs[NNODES] = ls[255];
}

__global__ __launch_bounds__(256) void k_scan3(const int* __restrict__ cnt,
                                               const int* __restrict__ bpre,
                                               int* __restrict__ offs, int* __restrict__ cur) {
    __shared__ int ls[256];
    const int i = blockIdx.x * 256 + threadIdx.x;
    const int v = (i < NNODES) ? cnt[i] : 0;
    ls[threadIdx.x] = v;
    __syncthreads();
    for (int d = 1; d < 256; d <<= 1) {
        int x = (threadIdx.x >= d) ? ls[threadIdx.x - d] : 0;
        __syncthreads();
        ls[threadIdx.x] += x;
        __syncthreads();
    }
    if (i < NNODES) {
        const int excl = ls[threadIdx.x] - v + bpre[blockIdx.x];
        offs[i] = excl;
        cur[i] = excl;
    }
}

__global__ void k_fill(const int* __restrict__ srcv, const int* __restrict__ dstv,
                       const int* __restrict__ attr, int* __restrict__ cur,
                       int* __restrict__ csr) {
    for (int e = blockIdx.x * blockDim.x + threadIdx.x; e < NEDGES; e += gridDim.x * blockDim.x) {
        int d = dstv[e];
        int pos = atomicAdd(&cur[d], 1);
        csr[pos] = (srcv[e] & 0xFFFF) | (attr[e] << 16);
    }
}

// ---------------- one-shot A packing ----------------
// cols 0..127 <- X_n (layer 0)
__global__ __launch_bounds__(256) void k_packA0(const float* __restrict__ X,
                                                unsigned short* __restrict__ Ab) {
    const int idx = blockIdx.x * 256 + threadIdx.x;   // < N*128
    const int r = idx >> 7, c = idx & 127;
    Ab[(size_t)r * KPAD + c] = f2b(X[idx]);
}

// cols 128..199 <- PE | zeros (layer-invariant, written once)
__global__ __launch_bounds__(256) void k_packPE(const float* __restrict__ PE,
                                                unsigned short* __restrict__ Ab) {
    const int idx = blockIdx.x * 256 + threadIdx.x;
    if (idx >= NNODES * 72) return;
    const int r = idx / 72, q = idx % 72;   // col = 128+q
    const float v = (q < PEDIM) ? PE[(size_t)r * PEDIM + q] : 0.f;
    Ab[(size_t)r * KPAD + DIM + q] = f2b(v);
}

// ---------------- per-layer parameter prep ----------------
// Btg[n=128][KPAD] bf16: Btg[n][k] = (k<128 ? linW[k][n] : k<165 ? (peW@linW)[k-128][n] : 0)
__global__ __launch_bounds__(256) void k_params(
    const float* __restrict__ linW, const float* __restrict__ peW,
    const float* __restrict__ peb, const float* __restrict__ attn_e,
    const float* __restrict__ edge_emb,
    unsigned short* __restrict__ Btg, float* __restrict__ b2, float* __restrict__ et,
    float* __restrict__ gsum, float* __restrict__ gsumsq) {
    if (blockIdx.x < 100) {
        const int idx = blockIdx.x * 256 + threadIdx.x;   // 0..25599
        const int j = idx & 127;
        const int k = idx >> 7;                            // 0..199
        float v = 0.f;
        if (k < DIM) {
            v = linW[k * DIM + j];
        } else if (k < KTOT) {
            const int p = k - DIM;
            float s = 0.f;
            #pragma unroll 8
            for (int d = 0; d < DIM; ++d) s = fmaf(peW[p * DIM + d], linW[d * DIM + j], s);
            v = s;
        }
        Btg[(size_t)j * KPAD + k] = f2b(v);
    } else {
        const int t = threadIdx.x;
        if (t < DIM) {
            float s = 0.f;
            #pragma unroll 8
            for (int d = 0; d < DIM; ++d) s = fmaf(peb[d], linW[d * DIM + t], s);
            b2[t] = s;
            gsum[t] = 0.f;
            gsumsq[t] = 0.f;
        } else if (t < DIM + 9) {
            const int e = t - DIM;
            float s = 0.f;
            #pragma unroll 8
            for (int d = 0; d < DIM; ++d) s = fmaf(edge_emb[e * DIM + d], attn_e[d], s);
            et[e] = s;
        }
    }
}

// ---------------- MFMA GEMM: H(bf16) = A @ B + b2, plus hl/hr ----------------
// BM=64, N=128, K=192 (6x32). A/B staged via global_load_lds (pure linear copy).
__global__ __launch_bounds__(256) void k_gemm(
    const unsigned short* __restrict__ Ab16, const unsigned short* __restrict__ Btg,
    const float* __restrict__ b2, const float* __restrict__ attn_l,
    const float* __restrict__ attn_r,
    unsigned short* __restrict__ H, float* __restrict__ HL, float* __restrict__ HR) {
    __shared__ unsigned short Als[64 * KPAD];    // 25.6 KB
    __shared__ unsigned short Bls[DIM * KPAD];   // 51.2 KB
    const int tid = threadIdx.x;
    const int row0 = blockIdx.x * 64;

    {   // A: 1600 int4, B: 3200 int4, both exactly linear (lane-contiguous)
        const int4* ga = (const int4*)(Ab16 + (size_t)row0 * KPAD);
        const int4* gb = (const int4*)Btg;
        int4* la = (int4*)Als;
        int4* lb = (int4*)Bls;
        for (int i = tid; i < 1600; i += 256) gload_lds16(ga + i, la + i);
        for (int i = tid; i < 3200; i += 256) gload_lds16(gb + i, lb + i);
    }
    __syncthreads();

    const int w = tid >> 6, l = tid & 63;
    const int c = l & 15;     // A-row-in-tile / B-col / D-col
    const int g = l >> 4;     // k-subgroup / D-row-group
    f32x4 zero4 = {0.f, 0.f, 0.f, 0.f};
    f32x4 acc[8];
    #pragma unroll
    for (int t = 0; t < 8; ++t) acc[t] = zero4;

    const unsigned short* aRow = Als + (size_t)(w * 16 + c) * KPAD + g * 8;
    #pragma unroll
    for (int s = 0; s < 6; ++s) {
        const bf16x8 a = *(const bf16x8*)(aRow + s * 32);
        #pragma unroll
        for (int t = 0; t < 8; ++t) {
            const bf16x8 b = *(const bf16x8*)(Bls + (size_t)(t * 16 + c) * KPAD + s * 32 + g * 8);
            acc[t] = __builtin_amdgcn_mfma_f32_16x16x32_bf16(a, b, acc[t], 0, 0, 0);
        }
    }

    float b2v[8], alv[8], arv[8];
    #pragma unroll
    for (int t = 0; t < 8; ++t) {
        b2v[t] = b2[t * 16 + c];
        alv[t] = attn_l[t * 16 + c];
        arv[t] = attn_r[t * 16 + c];
    }
    #pragma unroll
    for (int t = 0; t < 8; ++t)
        #pragma unroll
        for (int j = 0; j < 4; ++j) acc[t][j] += b2v[t];

    #pragma unroll
    for (int j = 0; j < 4; ++j) {
        float sl = 0.f, sr = 0.f;
        #pragma unroll
        for (int t = 0; t < 8; ++t) { sl = fmaf(acc[t][j], alv[t], sl); sr = fmaf(acc[t][j], arv[t], sr); }
        #pragma unroll
        for (int m = 1; m < 16; m <<= 1) {
            sl += __shfl_xor(sl, m, 64);
            sr += __shfl_xor(sr, m, 64);
        }
        const int grow = row0 + w * 16 + g * 4 + j;
        if (grow < NNODES && c == 0) { HL[grow] = sl; HR[grow] = sr; }
    }

    // repack D tile -> bf16 via LDS (overlay on Als), then coalesced store
    __syncthreads();
    unsigned short* Hls = Als;
    #pragma unroll
    for (int t = 0; t < 8; ++t)
        #pragma unroll
        for (int j = 0; j < 4; ++j)
            Hls[(w * 16 + g * 4 + j) * HSTR + t * 16 + c] = f2b(acc[t][j]);
    __syncthreads();
    #pragma unroll
    for (int kb = 0; kb < 4; ++kb) {
        const int idx = tid + kb * 256;         // 0..1023
        const int r = idx >> 4, kc = idx & 15;
        const int grow = row0 + r;
        if (grow < NNODES) {
            const int4 v = *(const int4*)(Hls + r * HSTR + kc * 8);
            ((int4*)(H + ((size_t)grow << 7)))[kc] = v;
        }
    }
}

// ---------------- per-node softmax + aggregation (bf16 H gather) ----------------
__global__ __launch_bounds__(256) void k_agg(
    const int* __restrict__ offs, const int* __restrict__ csr,
    const float* __restrict__ HL, const float* __restrict__ HR,
    const float* __restrict__ et, const unsigned short* __restrict__ H,
    const float* __restrict__ bias, float* __restrict__ OUT) {
    const int lane = threadIdx.x & 63;
    const int node = blockIdx.x * 4 + (threadIdx.x >> 6);
    if (node >= NNODES) return;
    const int off0 = offs[node];
    const int deg = offs[node + 1] - off0;

    const float hri = HR[node];
    float myA = 0.f;
    int myE = 0;
    float mx = -1e30f;
    for (int j = lane; j < deg; j += 64) {
        const int en = csr[off0 + j];
        float al = HL[en & 0xFFFF] + hri + et[en >> 16];
        al = al > 0.f ? al : 0.2f * al;
        if (j < 64) { myA = al; myE = en; }
        mx = fmaxf(mx, al);
    }
    #pragma unroll
    for (int m = 1; m < 64; m <<= 1) mx = fmaxf(mx, __shfl_xor(mx, m, 64));

    float s = 0.f, wv = 0.f;
    if (deg <= 64) {
        wv = (lane < deg) ? __expf(myA - mx) : 0.f;
        s = wv;
    } else {
        for (int j = lane; j < deg; j += 64) {
            const int en = csr[off0 + j];
            float al = HL[en & 0xFFFF] + hri + et[en >> 16];
            al = al > 0.f ? al : 0.2f * al;
            s += __expf(al - mx);
        }
    }
    #pragma unroll
    for (int m = 1; m < 64; m <<= 1) s += __shfl_xor(s, m, 64);
    const float invd = (deg > 0) ? 1.f / s : 0.f;
    wv *= invd;

    // accumulation: 4 edge-groups x 16 lanes; each lane: one int4 = 8 bf16 cols
    const int eg = lane >> 4, c = lane & 15;
    float a[8];
    #pragma unroll
    for (int t = 0; t < 8; ++t) a[t] = 0.f;
    for (int jb = 0; jb < deg; jb += 4) {
        const int j = jb + eg;
        const bool valid = j < deg;
        float wgt = 0.f;
        int src = 0;
        if (deg <= 64) {
            wgt = __shfl(wv, j & 63, 64);
            src = __shfl(myE, j & 63, 64) & 0xFFFF;
            if (!valid) wgt = 0.f;
        } else if (valid) {
            const int en = csr[off0 + j];
            float al = HL[en & 0xFFFF] + hri + et[en >> 16];
            al = al > 0.f ? al : 0.2f * al;
            wgt = __expf(al - mx) * invd;
            src = en & 0xFFFF;
        }
        if (valid) {
            const int4 hv = *(const int4*)(H + ((size_t)src << 7) + (c << 3));
            const unsigned int ux = hv.x, uy = hv.y, uz = hv.z, uw = hv.w;
            a[0] = fmaf(wgt, __uint_as_float(ux << 16), a[0]);
            a[1] = fmaf(wgt, __uint_as_float(ux & 0xFFFF0000u), a[1]);
            a[2] = fmaf(wgt, __uint_as_float(uy << 16), a[2]);
            a[3] = fmaf(wgt, __uint_as_float(uy & 0xFFFF0000u), a[3]);
            a[4] = fmaf(wgt, __uint_as_float(uz << 16), a[4]);
            a[5] = fmaf(wgt, __uint_as_float(uz & 0xFFFF0000u), a[5]);
            a[6] = fmaf(wgt, __uint_as_float(uw << 16), a[6]);
            a[7] = fmaf(wgt, __uint_as_float(uw & 0xFFFF0000u), a[7]);
        }
    }
    #pragma unroll
    for (int m = 16; m < 64; m <<= 1)
        #pragma unroll
        for (int t = 0; t < 8; ++t) a[t] += __shfl_xor(a[t], m, 64);
    if (eg == 0) {
        const float4 b0 = *(const float4*)&bias[c * 8];
        const float4 b1 = *(const float4*)&bias[c * 8 + 4];
        float4 o0 = make_float4(a[0] + b0.x, a[1] + b0.y, a[2] + b0.z, a[3] + b0.w);
        float4 o1 = make_float4(a[4] + b1.x, a[5] + b1.y, a[6] + b1.z, a[7] + b1.w);
        float4* op = (float4*)&OUT[(size_t)node * DIM + c * 8];
        op[0] = o0; op[1] = o1;
    }
}

// ---------------- BN stats ----------------
__global__ __launch_bounds__(256) void k_bnstats(
    const float* __restrict__ OUT, float* __restrict__ gsum, float* __restrict__ gsumsq) {
    __shared__ float ls[256], ls2[256];
    const int c = threadIdx.x & 127;
    const int half = threadIdx.x >> 7;
    const int rend = min(NNODES, (int)(blockIdx.x * 256 + 256));
    float s = 0.f, s2 = 0.f;
    for (int r = blockIdx.x * 256 + half; r < rend; r += 2) {
        const float v = OUT[(size_t)r * DIM + c];
        s += v;
        s2 = fmaf(v, v, s2);
    }
    ls[threadIdx.x] = s;
    ls2[threadIdx.x] = s2;
    __syncthreads();
    if (half == 0) {
        atomicAdd(&gsum[c], ls[c] + ls[c + 128]);
        atomicAdd(&gsumsq[c], ls2[c] + ls2[c + 128]);
    }
}

// ---------------- apply BN + residual (also packs next layer's A cols 0..127) ----------------
__global__ __launch_bounds__(256) void k_apply_bn(
    const float* __restrict__ OUT, const float* __restrict__ XPREV,
    const float* __restrict__ gsum, const float* __restrict__ gsumsq,
    const float* __restrict__ gamma, const float* __restrict__ beta,
    float* __restrict__ XNEXT, unsigned short* __restrict__ Ab) {
    const int idx = blockIdx.x * 256 + threadIdx.x;
    const int r = idx >> 7, c = idx & 127;
    const float mu = gsum[c] * (1.f / NNODES);
    const float var = gsumsq[c] * (1.f / NNODES) - mu * mu;
    const float sc = gamma[c] * rsqrtf(var + 1e-5f);
    const float xn = (OUT[idx] - mu) * sc + beta[c] + XPREV[idx];
    XNEXT[idx] = xn;
    Ab[(size_t)r * KPAD + c] = f2b(xn);
}

__global__ __launch_bounds__(256) void k_apply_last(
    const float* __restrict__ OUT, const float* __restrict__ XPREV, float* __restrict__ XF) {
    const int idx = blockIdx.x * 256 + threadIdx.x;
    XF[idx] = OUT[idx] + XPREV[idx];
}

// ---------------- host ----------------
extern "C" void kernel_launch(void* const* d_in, const int* in_sizes, int n_in,
                              void* d_out, int out_size, void* d_ws, size_t ws_size,
                              hipStream_t stream) {
    const float* X_n      = (const float*)d_in[0];
    const float* PE       = (const float*)d_in[1];
    const int*   eidx     = (const int*)d_in[2];
    const int*   eattr    = (const int*)d_in[3];
    const float* edge_emb = (const float*)d_in[4];
    const float* pe_W     = (const float*)d_in[5];
    const float* pe_b     = (const float*)d_in[6];
    const float* lin_W    = (const float*)d_in[7];
    const float* attn_l   = (const float*)d_in[8];
    const float* attn_r   = (const float*)d_in[9];
    const float* attn_e   = (const float*)d_in[10];
    const float* bias     = (const float*)d_in[11];
    const float* bng      = (const float*)d_in[12];
    const float* bnb      = (const float*)d_in[13];

    if (ws_size < WS_NEED) return;

    char* ws = (char*)d_ws;
    float* xbuf   = (float*)(ws + OFF_X);
    unsigned short* hbuf = (unsigned short*)(ws + OFF_H);
    float* obuf   = (float*)(ws + OFF_O);
    unsigned short* Ab16 = (unsigned short*)(ws + OFF_AB);
    float* hl     = (float*)(ws + OFF_HL);
    float* hr     = (float*)(ws + OFF_HR);
    int*   offs   = (int*)(ws + OFF_OFFS);
    int*   cur    = (int*)(ws + OFF_CUR);
    int*   csr    = (int*)(ws + OFF_CSR);
    unsigned short* Btg = (unsigned short*)(ws + OFF_BTG);
    float* b2     = (float*)(ws + OFF_B2);
    float* et     = (float*)(ws + OFF_ET);
    float* gsum   = (float*)(ws + OFF_GS);
    float* gsumsq = (float*)(ws + OFF_GS2);
    int*   bsum   = (int*)(ws + OFF_BS);
    int*   bpre   = (int*)(ws + OFF_BP);

    const int* srcv = eidx;
    const int* dstv = eidx + NEDGES;

    hipLaunchKernelGGL(k_zero_int, dim3(256), dim3(256), 0, stream, cur, NNODES);
    hipLaunchKernelGGL(k_count, dim3(1024), dim3(256), 0, stream, dstv, cur);
    hipLaunchKernelGGL(k_scan1, dim3(NSB), dim3(256), 0, stream, cur, bsum);
    hipLaunchKernelGGL(k_scan2, dim3(1), dim3(256), 0, stream, bsum, bpre, offs);
    hipLaunchKernelGGL(k_scan3, dim3(NSB), dim3(256), 0, stream, cur, bpre, offs, cur);
    hipLaunchKernelGGL(k_fill, dim3(1024), dim3(256), 0, stream, srcv, dstv, eattr, cur, csr);
    hipLaunchKernelGGL(k_packPE, dim3((NNODES * 72 + 255) / 256), dim3(256), 0, stream, PE, Ab16);
    hipLaunchKernelGGL(k_packA0, dim3(NNODES * DIM / 256), dim3(256), 0, stream, X_n, Ab16);

    const float* xin = X_n;
    for (int l = 0; l < NLAYERS; ++l) {
        hipLaunchKernelGGL(k_params, dim3(101), dim3(256), 0, stream,
                           lin_W + (size_t)l * DIM * DIM, pe_W + (size_t)l * PEDIM * DIM,
                           pe_b + (size_t)l * DIM, attn_e + (size_t)l * DIM,
                           edge_emb + (size_t)l * 9 * DIM,
                           Btg, b2, et, gsum, gsumsq);
        hipLaunchKernelGGL(k_gemm, dim3((NNODES + 63) / 64), dim3(256), 0, stream,
                           Ab16, Btg, b2, attn_l + (size_t)l * DIM, attn_r + (size_t)l * DIM,
                           hbuf, hl, hr);
        hipLaunchKernelGGL(k_agg, dim3((NNODES + 3) / 4), dim3(256), 0, stream,
                           offs, csr, hl, hr, et, hbuf, bias + (size_t)l * DIM, obuf);
        if (l < NLAYERS - 1) {
            hipLaunchKernelGGL(k_bnstats, dim3((NNODES + 255) / 256), dim3(256), 0, stream,
                               obuf, gsum, gsumsq);
            hipLaunchKernelGGL(k_apply_bn, dim3(NNODES * DIM / 256), dim3(256), 0, stream,
                               obuf, xin, gsum, gsumsq, bng + (size_t)l * DIM, bnb + (size_t)l * DIM,
                               xbuf, Ab16);
            xin = xbuf;
        } else {
            hipLaunchKernelGGL(k_apply_last, dim3(NNODES * DIM / 256), dim3(256), 0, stream,
                               obuf, xin, (float*)d_out);
        }
    }
}

// Round 5
// 364.716 us; speedup vs baseline: 2.6581x; 1.0275x over previous
//
#include <hip/hip_runtime.h>
#include <hip/hip_bf16.h>
#include <math.h>

#define NNODES 50000
#define NEDGES 640000
#define DIM    128
#define PEDIM  37
#define KTOT   165   // DIM + PEDIM
#define KPAD   200   // bf16 row stride for A and B (400 B = 25 int4, 16B-aligned)
#define HSTR   136   // LDS repack stride (272 B, 16B-aligned, conflict-benign)
#define NLAYERS 3
#define NSB    ((NNODES + 255) / 256)     // 196 scan blocks
#define NPACKB ((NNODES * 25 + 255) / 256) // 4883 pack blocks
#define NBN    (NNODES * DIM / 256)        // 25000 BN-apply blocks

using bf16x8 = __attribute__((ext_vector_type(8))) short;
using f32x4  = __attribute__((ext_vector_type(4))) float;

static constexpr size_t alignup(size_t x) { return (x + 255) & ~size_t(255); }
static constexpr size_t OFF_X    = 0;                                              // fp32 x (residual)
static constexpr size_t OFF_H    = alignup(OFF_X   + (size_t)NNODES * DIM * 4);    // bf16 H
static constexpr size_t OFF_O    = alignup(OFF_H   + (size_t)NNODES * DIM * 2);    // fp32 out
static constexpr size_t OFF_AB   = alignup(OFF_O   + (size_t)NNODES * DIM * 4);    // bf16 A=[x|PE|0]
static constexpr size_t OFF_HL   = alignup(OFF_AB  + (size_t)NNODES * KPAD * 2);
static constexpr size_t OFF_HR   = alignup(OFF_HL  + (size_t)NNODES * 4);
static constexpr size_t OFF_OFFS = alignup(OFF_HR  + (size_t)NNODES * 4);
static constexpr size_t OFF_CUR  = alignup(OFF_OFFS + (size_t)(NNODES + 1) * 4);
static constexpr size_t OFF_CSR  = alignup(OFF_CUR + (size_t)NNODES * 4);
static constexpr size_t OFF_BTG  = alignup(OFF_CSR + (size_t)NEDGES * 4);
static constexpr size_t OFF_B2   = alignup(OFF_BTG + (size_t)DIM * KPAD * 2);
static constexpr size_t OFF_ET   = alignup(OFF_B2  + (size_t)DIM * 4);
static constexpr size_t OFF_GS   = alignup(OFF_ET  + 16 * 4);                      // 4*128 floats: gs0,gsq0,gs1,gsq1
static constexpr size_t OFF_BS   = alignup(OFF_GS  + 512 * 4);
static constexpr size_t OFF_BP   = alignup(OFF_BS  + 256 * 4);
static constexpr size_t WS_NEED  = alignup(OFF_BP  + 256 * 4);

__device__ inline unsigned short f2b(float f) {
    union { float f; unsigned int u; } x; x.f = f;
    unsigned int r = x.u + 0x7FFFu + ((x.u >> 16) & 1u);
    return (unsigned short)(r >> 16);
}
__device__ inline unsigned int pack2(float a, float b) {
    return (unsigned int)f2b(a) | ((unsigned int)f2b(b) << 16);
}

__device__ inline void gload_lds16(const void* g, void* l) {
    __builtin_amdgcn_global_load_lds((const __attribute__((address_space(1))) void*)g,
                                     (__attribute__((address_space(3))) void*)l, 16, 0, 0);
}

// ---------------- CSR build ----------------

__global__ void k_zero_int(int* __restrict__ p, int n) {
    for (int i = blockIdx.x * blockDim.x + threadIdx.x; i < n; i += gridDim.x * blockDim.x)
        p[i] = 0;
}

__global__ void k_count(const int* __restrict__ dstv, int* __restrict__ cnt) {
    for (int e = blockIdx.x * blockDim.x + threadIdx.x; e < NEDGES; e += gridDim.x * blockDim.x)
        atomicAdd(&cnt[dstv[e]], 1);
}

__global__ __launch_bounds__(256) void k_scan1(const int* __restrict__ cnt, int* __restrict__ bsum) {
    __shared__ int ls[256];
    const int i = blockIdx.x * 256 + threadIdx.x;
    ls[threadIdx.x] = (i < NNODES) ? cnt[i] : 0;
    __syncthreads();
    for (int d = 128; d > 0; d >>= 1) {
        if (threadIdx.x < d) ls[threadIdx.x] += ls[threadIdx.x + d];
        __syncthreads();
    }
    if (threadIdx.x == 0) bsum[blockIdx.x] = ls[0];
}

__global__ __launch_bounds__(256) void k_scan2(const int* __restrict__ bsum,
                                               int* __restrict__ bpre, int* __restrict__ offs) {
    __shared__ int ls[256];
    const int t = threadIdx.x;
    ls[t] = (t < NSB) ? bsum[t] : 0;
    __syncthreads();
    for (int d = 1; d < 256; d <<= 1) {
        int v = (t >= d) ? ls[t - d] : 0;
        __syncthreads();
        ls[t] += v;
        __syncthreads();
    }
    bpre[t] = (t == 0) ? 0 : ls[t - 1];
    if (t == 255) offs[NNODES] = ls[255];
}

__global__ __launch_bounds__(256) void k_scan3(const int* __restrict__ cnt,
                                               const int* __restrict__ bpre,
                                               int* __restrict__ offs, int* __restrict__ cur) {
    __shared__ int ls[256];
    const int i = blockIdx.x * 256 + threadIdx.x;
    const int v = (i < NNODES) ? cnt[i] : 0;
    ls[threadIdx.x] = v;
    __syncthreads();
    for (int d = 1; d < 256; d <<= 1) {
        int x = (threadIdx.x >= d) ? ls[threadIdx.x - d] : 0;
        __syncthreads();
        ls[threadIdx.x] += x;
        __syncthreads();
    }
    if (i < NNODES) {
        const int excl = ls[threadIdx.x] - v + bpre[blockIdx.x];
        offs[i] = excl;
        cur[i] = excl;
    }
}

__global__ void k_fill(const int* __restrict__ srcv, const int* __restrict__ dstv,
                       const int* __restrict__ attr, int* __restrict__ cur,
                       int* __restrict__ csr) {
    for (int e = blockIdx.x * blockDim.x + threadIdx.x; e < NEDGES; e += gridDim.x * blockDim.x) {
        int d = dstv[e];
        int pos = atomicAdd(&cur[d], 1);
        csr[pos] = (srcv[e] & 0xFFFF) | (attr[e] << 16);
    }
}

// ---------------- shared params body ----------------
// pb 0..99: Btg rows; pb==100: b2, et (misc)
__device__ inline void params_body(int pb, int tid,
    const float* __restrict__ linW, const float* __restrict__ peW,
    const float* __restrict__ peb, const float* __restrict__ attn_e,
    const float* __restrict__ edge_emb,
    unsigned short* __restrict__ Btg, float* __restrict__ b2, float* __restrict__ et) {
    if (pb < 100) {
        const int idx = pb * 256 + tid;   // 0..25599
        const int j = idx & 127;
        const int k = idx >> 7;           // 0..199
        float v = 0.f;
        if (k < DIM) {
            v = linW[k * DIM + j];
        } else if (k < KTOT) {
            const int p = k - DIM;
            float s = 0.f;
            #pragma unroll 8
            for (int d = 0; d < DIM; ++d) s = fmaf(peW[p * DIM + d], linW[d * DIM + j], s);
            v = s;
        }
        Btg[(size_t)j * KPAD + k] = f2b(v);
    } else {
        if (tid < DIM) {
            float s = 0.f;
            #pragma unroll 8
            for (int d = 0; d < DIM; ++d) s = fmaf(peb[d], linW[d * DIM + tid], s);
            b2[tid] = s;
        } else if (tid < DIM + 9) {
            const int e = tid - DIM;
            float s = 0.f;
            #pragma unroll 8
            for (int d = 0; d < DIM; ++d) s = fmaf(edge_emb[e * DIM + d], attn_e[d], s);
            et[e] = s;
        }
    }
}

// ---------------- pack A (X|PE|0 -> bf16) + layer-0 params + zero BN accumulators ----------------
__global__ __launch_bounds__(256) void k_pack(
    const float* __restrict__ X, const float* __restrict__ PE,
    const float* __restrict__ linW, const float* __restrict__ peW,
    const float* __restrict__ peb, const float* __restrict__ attn_e,
    const float* __restrict__ edge_emb,
    unsigned short* __restrict__ Ab, unsigned short* __restrict__ Btg,
    float* __restrict__ b2, float* __restrict__ et, float* __restrict__ gs) {
    if ((int)blockIdx.x < NPACKB) {
        const int idx = blockIdx.x * 256 + threadIdx.x;
        if (idx >= NNODES * 25) return;
        const int r = idx / 25, kc = idx % 25;
        int4 pk;
        if (kc < 16) {
            const float4* xp = (const float4*)&X[(size_t)r * DIM + kc * 8];
            const float4 v0 = xp[0], v1 = xp[1];
            pk.x = pack2(v0.x, v0.y); pk.y = pack2(v0.z, v0.w);
            pk.z = pack2(v1.x, v1.y); pk.w = pack2(v1.z, v1.w);
        } else {
            float f[8];
            #pragma unroll
            for (int i = 0; i < 8; ++i) {
                const int k = kc * 8 + i;
                f[i] = (k < KTOT) ? PE[(size_t)r * PEDIM + (k - DIM)] : 0.f;
            }
            pk.x = pack2(f[0], f[1]); pk.y = pack2(f[2], f[3]);
            pk.z = pack2(f[4], f[5]); pk.w = pack2(f[6], f[7]);
        }
        ((int4*)(Ab + (size_t)r * KPAD))[kc] = pk;
    } else {
        const int pb = blockIdx.x - NPACKB;
        if (pb == 100) {   // zero all four 128-float BN accumulators
            gs[threadIdx.x] = 0.f;
            gs[threadIdx.x + 256] = 0.f;
        }
        params_body(pb, threadIdx.x, linW, peW, peb, attn_e, edge_emb, Btg, b2, et);
    }
}

// ---------------- MFMA GEMM: H(bf16) = A @ B + b2, plus hl/hr ----------------
__global__ __launch_bounds__(256) void k_gemm(
    const unsigned short* __restrict__ Ab16, const unsigned short* __restrict__ Btg,
    const float* __restrict__ b2, const float* __restrict__ attn_l,
    const float* __restrict__ attn_r,
    unsigned short* __restrict__ H, float* __restrict__ HL, float* __restrict__ HR) {
    __shared__ unsigned short Als[64 * KPAD];    // 25.6 KB
    __shared__ unsigned short Bls[DIM * KPAD];   // 51.2 KB
    const int tid = threadIdx.x;
    const int row0 = blockIdx.x * 64;

    {   // A: 1600 int4, B: 3200 int4, both exactly linear (lane-contiguous)
        const int4* ga = (const int4*)(Ab16 + (size_t)row0 * KPAD);
        const int4* gb = (const int4*)Btg;
        int4* la = (int4*)Als;
        int4* lb = (int4*)Bls;
        for (int i = tid; i < 1600; i += 256) gload_lds16(ga + i, la + i);
        for (int i = tid; i < 3200; i += 256) gload_lds16(gb + i, lb + i);
    }
    __syncthreads();

    const int w = tid >> 6, l = tid & 63;
    const int c = l & 15;     // A-row-in-tile / B-col / D-col
    const int g = l >> 4;     // k-subgroup / D-row-group
    f32x4 zero4 = {0.f, 0.f, 0.f, 0.f};
    f32x4 acc[8];
    #pragma unroll
    for (int t = 0; t < 8; ++t) acc[t] = zero4;

    const unsigned short* aRow = Als + (size_t)(w * 16 + c) * KPAD + g * 8;
    #pragma unroll
    for (int s = 0; s < 6; ++s) {
        const bf16x8 a = *(const bf16x8*)(aRow + s * 32);
        #pragma unroll
        for (int t = 0; t < 8; ++t) {
            const bf16x8 b = *(const bf16x8*)(Bls + (size_t)(t * 16 + c) * KPAD + s * 32 + g * 8);
            acc[t] = __builtin_amdgcn_mfma_f32_16x16x32_bf16(a, b, acc[t], 0, 0, 0);
        }
    }

    float b2v[8], alv[8], arv[8];
    #pragma unroll
    for (int t = 0; t < 8; ++t) {
        b2v[t] = b2[t * 16 + c];
        alv[t] = attn_l[t * 16 + c];
        arv[t] = attn_r[t * 16 + c];
    }
    #pragma unroll
    for (int t = 0; t < 8; ++t)
        #pragma unroll
        for (int j = 0; j < 4; ++j) acc[t][j] += b2v[t];

    #pragma unroll
    for (int j = 0; j < 4; ++j) {
        float sl = 0.f, sr = 0.f;
        #pragma unroll
        for (int t = 0; t < 8; ++t) { sl = fmaf(acc[t][j], alv[t], sl); sr = fmaf(acc[t][j], arv[t], sr); }
        #pragma unroll
        for (int m = 1; m < 16; m <<= 1) {
            sl += __shfl_xor(sl, m, 64);
            sr += __shfl_xor(sr, m, 64);
        }
        const int grow = row0 + w * 16 + g * 4 + j;
        if (grow < NNODES && c == 0) { HL[grow] = sl; HR[grow] = sr; }
    }

    // repack D tile -> bf16 via LDS (overlay on Als), then coalesced store
    __syncthreads();
    unsigned short* Hls = Als;
    #pragma unroll
    for (int t = 0; t < 8; ++t)
        #pragma unroll
        for (int j = 0; j < 4; ++j)
            Hls[(w * 16 + g * 4 + j) * HSTR + t * 16 + c] = f2b(acc[t][j]);
    __syncthreads();
    #pragma unroll
    for (int kb = 0; kb < 4; ++kb) {
        const int idx = tid + kb * 256;         // 0..1023
        const int r = idx >> 4, kc = idx & 15;
        const int grow = row0 + r;
        if (grow < NNODES) {
            const int4 v = *(const int4*)(Hls + r * HSTR + kc * 8);
            ((int4*)(H + ((size_t)grow << 7)))[kc] = v;
        }
    }
}

// ---------------- per-node softmax + aggregation (bf16 H gather) ----------------
// FINAL=0: OUT = agg + bias (fp32 obuf). FINAL=1: OUT = agg + bias + xprev -> d_out.
template<int FINAL>
__global__ __launch_bounds__(256) void k_agg(
    const int* __restrict__ offs, const int* __restrict__ csr,
    const float* __restrict__ HL, const float* __restrict__ HR,
    const float* __restrict__ et, const unsigned short* __restrict__ H,
    const float* __restrict__ bias, const float* __restrict__ xprev,
    float* __restrict__ OUT) {
    const int lane = threadIdx.x & 63;
    const int node = blockIdx.x * 4 + (threadIdx.x >> 6);
    if (node >= NNODES) return;
    const int off0 = offs[node];
    const int deg = offs[node + 1] - off0;

    const float hri = HR[node];
    float myA = 0.f;
    int myE = 0;
    float mx = -1e30f;
    for (int j = lane; j < deg; j += 64) {
        const int en = csr[off0 + j];
        float al = HL[en & 0xFFFF] + hri + et[en >> 16];
        al = al > 0.f ? al : 0.2f * al;
        if (j < 64) { myA = al; myE = en; }
        mx = fmaxf(mx, al);
    }
    #pragma unroll
    for (int m = 1; m < 64; m <<= 1) mx = fmaxf(mx, __shfl_xor(mx, m, 64));

    float s = 0.f, wv = 0.f;
    if (deg <= 64) {
        wv = (lane < deg) ? __expf(myA - mx) : 0.f;
        s = wv;
    } else {
        for (int j = lane; j < deg; j += 64) {
            const int en = csr[off0 + j];
            float al = HL[en & 0xFFFF] + hri + et[en >> 16];
            al = al > 0.f ? al : 0.2f * al;
            s += __expf(al - mx);
        }
    }
    #pragma unroll
    for (int m = 1; m < 64; m <<= 1) s += __shfl_xor(s, m, 64);
    const float invd = (deg > 0) ? 1.f / s : 0.f;
    wv *= invd;

    // accumulation: 8 edge-groups x 8 lanes; each lane: 2x int4 = 16 bf16 cols
    const int eg = lane >> 3, c = lane & 7;
    float a[16];
    #pragma unroll
    for (int t = 0; t < 16; ++t) a[t] = 0.f;
    for (int jb = 0; jb < deg; jb += 8) {
        const int j = jb + eg;
        const bool valid = j < deg;
        float wgt = 0.f;
        int src = 0;
        if (deg <= 64) {
            wgt = __shfl(wv, j & 63, 64);
            src = __shfl(myE, j & 63, 64) & 0xFFFF;
            if (!valid) wgt = 0.f;
        } else if (valid) {
            const int en = csr[off0 + j];
            float al = HL[en & 0xFFFF] + hri + et[en >> 16];
            al = al > 0.f ? al : 0.2f * al;
            wgt = __expf(al - mx) * invd;
            src = en & 0xFFFF;
        }
        if (valid) {
            const unsigned short* hp = H + ((size_t)src << 7) + (c << 4);
            const int4 h0 = *(const int4*)hp;
            const int4 h1 = *(const int4*)(hp + 8);
            const unsigned int u[8] = {(unsigned)h0.x, (unsigned)h0.y, (unsigned)h0.z, (unsigned)h0.w,
                                       (unsigned)h1.x, (unsigned)h1.y, (unsigned)h1.z, (unsigned)h1.w};
            #pragma unroll
            for (int q = 0; q < 8; ++q) {
                a[2 * q]     = fmaf(wgt, __uint_as_float(u[q] << 16), a[2 * q]);
                a[2 * q + 1] = fmaf(wgt, __uint_as_float(u[q] & 0xFFFF0000u), a[2 * q + 1]);
            }
        }
    }
    #pragma unroll
    for (int m = 8; m < 64; m <<= 1)
        #pragma unroll
        for (int t = 0; t < 16; ++t) a[t] += __shfl_xor(a[t], m, 64);
    if (eg == 0) {
        const float* bp = bias + (c << 4);
        float* op = OUT + ((size_t)node << 7) + (c << 4);
        #pragma unroll
        for (int q = 0; q < 4; ++q) {
            const float4 b = *(const float4*)(bp + q * 4);
            float4 o = make_float4(a[q * 4] + b.x, a[q * 4 + 1] + b.y,
                                   a[q * 4 + 2] + b.z, a[q * 4 + 3] + b.w);
            if (FINAL) {
                const float4 xp = *(const float4*)(xprev + ((size_t)node << 7) + (c << 4) + q * 4);
                o.x += xp.x; o.y += xp.y; o.z += xp.z; o.w += xp.w;
            }
            *(float4*)(op + q * 4) = o;
        }
    }
}

// ---------------- BN stats (into per-layer gs: [gsum(128) | gsumsq(128)]) ----------------
__global__ __launch_bounds__(256) void k_bnstats(
    const float* __restrict__ OUT, float* __restrict__ gs) {
    __shared__ float ls[256], ls2[256];
    const int c = threadIdx.x & 127;
    const int half = threadIdx.x >> 7;
    const int rend = min(NNODES, (int)(blockIdx.x * 256 + 256));
    float s = 0.f, s2 = 0.f;
    for (int r = blockIdx.x * 256 + half; r < rend; r += 2) {
        const float v = OUT[(size_t)r * DIM + c];
        s += v;
        s2 = fmaf(v, v, s2);
    }
    ls[threadIdx.x] = s;
    ls2[threadIdx.x] = s2;
    __syncthreads();
    if (half == 0) {
        atomicAdd(&gs[c], ls[c] + ls[c + 128]);
        atomicAdd(&gs[128 + c], ls2[c] + ls2[c + 128]);
    }
}

// ---------------- BN apply + residual + A-repack, fused with NEXT layer's params ----------------
__global__ __launch_bounds__(256) void k_apply_bn_params(
    const float* __restrict__ OUT, const float* __restrict__ XPREV,
    const float* __restrict__ gs, const float* __restrict__ gamma,
    const float* __restrict__ beta,
    float* __restrict__ XNEXT, unsigned short* __restrict__ Ab,
    const float* __restrict__ linW, const float* __restrict__ peW,
    const float* __restrict__ peb, const float* __restrict__ attn_e,
    const float* __restrict__ edge_emb,
    unsigned short* __restrict__ Btg, float* __restrict__ b2, float* __restrict__ et) {
    if ((int)blockIdx.x < NBN) {
        const int idx = blockIdx.x * 256 + threadIdx.x;
        const int r = idx >> 7, c = idx & 127;
        const float mu = gs[c] * (1.f / NNODES);
        const float var = gs[128 + c] * (1.f / NNODES) - mu * mu;
        const float sc = gamma[c] * rsqrtf(var + 1e-5f);
        const float xn = (OUT[idx] - mu) * sc + beta[c] + XPREV[idx];
        XNEXT[idx] = xn;
        Ab[(size_t)r * KPAD + c] = f2b(xn);
    } else {
        params_body(blockIdx.x - NBN, threadIdx.x, linW, peW, peb, attn_e, edge_emb, Btg, b2, et);
    }
}

// ---------------- host ----------------
extern "C" void kernel_launch(void* const* d_in, const int* in_sizes, int n_in,
                              void* d_out, int out_size, void* d_ws, size_t ws_size,
                              hipStream_t stream) {
    const float* X_n      = (const float*)d_in[0];
    const float* PE       = (const float*)d_in[1];
    const int*   eidx     = (const int*)d_in[2];
    const int*   eattr    = (const int*)d_in[3];
    const float* edge_emb = (const float*)d_in[4];
    const float* pe_W     = (const float*)d_in[5];
    const float* pe_b     = (const float*)d_in[6];
    const float* lin_W    = (const float*)d_in[7];
    const float* attn_l   = (const float*)d_in[8];
    const float* attn_r   = (const float*)d_in[9];
    const float* attn_e   = (const float*)d_in[10];
    const float* bias     = (const float*)d_in[11];
    const float* bng      = (const float*)d_in[12];
    const float* bnb      = (const float*)d_in[13];

    if (ws_size < WS_NEED) return;

    char* ws = (char*)d_ws;
    float* xbuf   = (float*)(ws + OFF_X);
    unsigned short* hbuf = (unsigned short*)(ws + OFF_H);
    float* obuf   = (float*)(ws + OFF_O);
    unsigned short* Ab16 = (unsigned short*)(ws + OFF_AB);
    float* hl     = (float*)(ws + OFF_HL);
    float* hr     = (float*)(ws + OFF_HR);
    int*   offs   = (int*)(ws + OFF_OFFS);
    int*   cur    = (int*)(ws + OFF_CUR);
    int*   csr    = (int*)(ws + OFF_CSR);
    unsigned short* Btg = (unsigned short*)(ws + OFF_BTG);
    float* b2     = (float*)(ws + OFF_B2);
    float* et     = (float*)(ws + OFF_ET);
    float* gs     = (float*)(ws + OFF_GS);   // gs + 256*l for layer l
    int*   bsum   = (int*)(ws + OFF_BS);
    int*   bpre   = (int*)(ws + OFF_BP);

    const int* srcv = eidx;
    const int* dstv = eidx + NEDGES;

    hipLaunchKernelGGL(k_zero_int, dim3(256), dim3(256), 0, stream, cur, NNODES);
    hipLaunchKernelGGL(k_count, dim3(1024), dim3(256), 0, stream, dstv, cur);
    hipLaunchKernelGGL(k_scan1, dim3(NSB), dim3(256), 0, stream, cur, bsum);
    hipLaunchKernelGGL(k_scan2, dim3(1), dim3(256), 0, stream, bsum, bpre, offs);
    hipLaunchKernelGGL(k_scan3, dim3(NSB), dim3(256), 0, stream, cur, bpre, offs, cur);
    hipLaunchKernelGGL(k_fill, dim3(1024), dim3(256), 0, stream, srcv, dstv, eattr, cur, csr);
    hipLaunchKernelGGL(k_pack, dim3(NPACKB + 101), dim3(256), 0, stream,
                       X_n, PE, lin_W, pe_W, pe_b, attn_e, edge_emb,
                       Ab16, Btg, b2, et, gs);

    const float* xin = X_n;
    for (int l = 0; l < NLAYERS; ++l) {
        hipLaunchKernelGGL(k_gemm, dim3((NNODES + 63) / 64), dim3(256), 0, stream,
                           Ab16, Btg, b2, attn_l + (size_t)l * DIM, attn_r + (size_t)l * DIM,
                           hbuf, hl, hr);
        if (l < NLAYERS - 1) {
            hipLaunchKernelGGL((k_agg<0>), dim3((NNODES + 3) / 4), dim3(256), 0, stream,
                               offs, csr, hl, hr, et, hbuf, bias + (size_t)l * DIM,
                               (const float*)nullptr, obuf);
            hipLaunchKernelGGL(k_bnstats, dim3(NSB), dim3(256), 0, stream,
                               obuf, gs + 256 * l);
            const int ln = l + 1;
            hipLaunchKernelGGL(k_apply_bn_params, dim3(NBN + 101), dim3(256), 0, stream,
                               obuf, xin, gs + 256 * l, bng + (size_t)l * DIM, bnb + (size_t)l * DIM,
                               xbuf, Ab16,
                               lin_W + (size_t)ln * DIM * DIM, pe_W + (size_t)ln * PEDIM * DIM,
                               pe_b + (size_t)ln * DIM, attn_e + (size_t)ln * DIM,
                               edge_emb + (size_t)ln * 9 * DIM,
                               Btg, b2, et);
            xin = xbuf;
        } else {
            hipLaunchKernelGGL((k_agg<1>), dim3((NNODES + 3) / 4), dim3(256), 0, stream,
                               offs, csr, hl, hr, et, hbuf, bias + (size_t)l * DIM,
                               xin, (float*)d_out);
        }
    }
}